// Round 1
// baseline (615.570 us; speedup 1.0000x reference)
//
#include <hip/hip_runtime.h>
#include <hip/hip_bf16.h>
#include <stdint.h>

#define B_ 4
#define S_ 2048
#define D_ 1024
#define H_ 16
#define HD_ 64

typedef __bf16 bf16_t;
typedef __bf16 bf16x8 __attribute__((ext_vector_type(8)));
typedef float f32x4 __attribute__((ext_vector_type(4)));

#define MFMA(a, b, c) __builtin_amdgcn_mfma_f32_16x16x32_bf16((a), (b), (c), 0, 0, 0)

__device__ __forceinline__ void gload_lds16(const void* g, void* l) {
  __builtin_amdgcn_global_load_lds(
      (const __attribute__((address_space(1))) uint32_t*)g,
      (__attribute__((address_space(3))) uint32_t*)l, 16, 0, 0);
}

// ---- weight transpose + convert: WT[n][k] = bf16(W[k][n]) -------------------
__global__ __launch_bounds__(256) void wt_kernel(const float* __restrict__ w,
                                                 bf16_t* __restrict__ wt) {
  __shared__ float t[32][33];
  const int tx = threadIdx.x & 31, ty = threadIdx.x >> 5;
  const int n0 = blockIdx.x * 32, k0 = blockIdx.y * 32;
#pragma unroll
  for (int i = 0; i < 4; i++)
    t[ty + i * 8][tx] = w[(size_t)(k0 + ty + i * 8) * D_ + n0 + tx];
  __syncthreads();
#pragma unroll
  for (int i = 0; i < 4; i++)
    wt[(size_t)(n0 + ty + i * 8) * D_ + k0 + tx] = (bf16_t)t[tx][ty + i * 8];
}

// ---- GEMM: C[8192x1024] = A[8192x1024] @ W + b ------------------------------
// MODE 0: A=f32 q,  out = bf16 Qh[(b*16+h)][s][hd] * 0.125
// MODE 1: A=f32 k,  out = bf16 Kh[(b*16+h)][s][hd]
// MODE 2: A=f32 v,  out = bf16 VT[(b*16+h)][hd][s]   (LDS-transposed epilogue)
// MODE 3: A=bf16 attn, out = f32 [m][n] + bias
template <int MODE>
__global__ __launch_bounds__(256) void gemm_k(const void* __restrict__ Av,
                                              const bf16_t* __restrict__ WT,
                                              const float* __restrict__ bias,
                                              void* __restrict__ Ov) {
  constexpr int K = D_;
  __shared__ bf16_t smem[17408];  // staging: A[128][64] + B[128][64]; MODE2 epi: [128][136]
  bf16_t* alds = smem;
  bf16_t* blds = smem + 8192;

  const int tid = threadIdx.x;
  const int w = tid >> 6, l = tid & 63;
  const int lr = l & 15, lg = l >> 4;
  const int wm = w >> 1, wn = w & 1;
  const int m0 = blockIdx.y * 128, n0 = blockIdx.x * 128;

  f32x4 acc[4][4];
#pragma unroll
  for (int mt = 0; mt < 4; mt++)
#pragma unroll
    for (int nt = 0; nt < 4; nt++) {
      f32x4 z = {0.f, 0.f, 0.f, 0.f};
      acc[mt][nt] = z;
    }

  for (int k0 = 0; k0 < K; k0 += 64) {
    // stage B tile (WT rows = n), swizzled source -> linear LDS
#pragma unroll
    for (int c = 0; c < 4; c++) {
      int ci = c * 256 + w * 64 + l;
      int row = ci >> 3, kc = ci & 7;
      int ks = kc ^ (row & 7);
      gload_lds16(WT + (size_t)(n0 + row) * K + k0 + ks * 8,
                  blds + (size_t)(c * 256 + w * 64) * 8);
    }
    // stage A tile
    if constexpr (MODE != 3) {
      const float* A = (const float*)Av;
#pragma unroll
      for (int c = 0; c < 4; c++) {
        int ci = c * 256 + tid;
        int row = ci >> 3, kc = ci & 7;
        int ks = kc ^ (row & 7);
        const float* src = A + (size_t)(m0 + row) * K + k0 + ks * 8;
        float4 x0 = ((const float4*)src)[0];
        float4 x1 = ((const float4*)src)[1];
        bf16x8 vv;
        vv[0] = (bf16_t)x0.x; vv[1] = (bf16_t)x0.y; vv[2] = (bf16_t)x0.z; vv[3] = (bf16_t)x0.w;
        vv[4] = (bf16_t)x1.x; vv[5] = (bf16_t)x1.y; vv[6] = (bf16_t)x1.z; vv[7] = (bf16_t)x1.w;
        *reinterpret_cast<bf16x8*>(alds + (size_t)ci * 8) = vv;
      }
    } else {
      const bf16_t* A = (const bf16_t*)Av;
#pragma unroll
      for (int c = 0; c < 4; c++) {
        int ci = c * 256 + w * 64 + l;
        int row = ci >> 3, kc = ci & 7;
        int ks = kc ^ (row & 7);
        gload_lds16(A + (size_t)(m0 + row) * K + k0 + ks * 8,
                    alds + (size_t)(c * 256 + w * 64) * 8);
      }
    }
    __syncthreads();
#pragma unroll
    for (int kk = 0; kk < 2; kk++) {
      bf16x8 af[4], bfr[4];
#pragma unroll
      for (int mt = 0; mt < 4; mt++) {
        int row = wm * 64 + mt * 16 + lr;
        int kc = kk * 4 + lg;
        af[mt] = *reinterpret_cast<const bf16x8*>(alds + row * 64 + ((kc ^ (row & 7)) * 8));
      }
#pragma unroll
      for (int nt = 0; nt < 4; nt++) {
        int row = wn * 64 + nt * 16 + lr;
        int kc = kk * 4 + lg;
        bfr[nt] = *reinterpret_cast<const bf16x8*>(blds + row * 64 + ((kc ^ (row & 7)) * 8));
      }
#pragma unroll
      for (int mt = 0; mt < 4; mt++)
#pragma unroll
        for (int nt = 0; nt < 4; nt++)
          acc[mt][nt] = MFMA(af[mt], bfr[nt], acc[mt][nt]);
    }
    __syncthreads();
  }

  float bn[4];
#pragma unroll
  for (int nt = 0; nt < 4; nt++) bn[nt] = bias[n0 + wn * 64 + nt * 16 + lr];

  if constexpr (MODE == 0 || MODE == 1) {
    bf16_t* out = (bf16_t*)Ov;
#pragma unroll
    for (int mt = 0; mt < 4; mt++)
#pragma unroll
      for (int nt = 0; nt < 4; nt++)
#pragma unroll
        for (int r = 0; r < 4; r++) {
          int m = m0 + wm * 64 + mt * 16 + lg * 4 + r;
          int n = n0 + wn * 64 + nt * 16 + lr;
          float v = acc[mt][nt][r] + bn[nt];
          if constexpr (MODE == 0) v *= 0.125f;  // 1/sqrt(HD), exact in bf16
          int b = m >> 11, s = m & 2047, h = n >> 6, hd = n & 63;
          out[(((size_t)(b * H_ + h) * S_ + s) << 6) + hd] = (bf16_t)v;
        }
  } else if constexpr (MODE == 3) {
    float* out = (float*)Ov;
#pragma unroll
    for (int mt = 0; mt < 4; mt++)
#pragma unroll
      for (int nt = 0; nt < 4; nt++)
#pragma unroll
        for (int r = 0; r < 4; r++) {
          int m = m0 + wm * 64 + mt * 16 + lg * 4 + r;
          int n = n0 + wn * 64 + nt * 16 + lr;
          out[(size_t)m * D_ + n] = acc[mt][nt][r] + bn[nt];
        }
  } else {  // MODE 2: transpose in LDS, write VT[(b*16+h)][hd][s]
    __syncthreads();
#pragma unroll
    for (int mt = 0; mt < 4; mt++)
#pragma unroll
      for (int nt = 0; nt < 4; nt++)
#pragma unroll
        for (int r = 0; r < 4; r++) {
          int ml = wm * 64 + mt * 16 + lg * 4 + r;
          int nl = wn * 64 + nt * 16 + lr;
          smem[nl * 136 + ml] = (bf16_t)(acc[mt][nt][r] + bn[nt]);
        }
    __syncthreads();
    bf16_t* out = (bf16_t*)Ov;
    const int b = m0 >> 11, sbase = m0 & 2047;
#pragma unroll
    for (int c = 0; c < 8; c++) {
      int ci = c * 256 + tid;
      int dl = ci >> 4, sc = ci & 15;
      int n = n0 + dl, h = n >> 6, hd = n & 63;
      bf16x8 v = *reinterpret_cast<const bf16x8*>(smem + dl * 136 + sc * 8);
      *reinterpret_cast<bf16x8*>(out + ((size_t)((b * H_ + h) << 6) + hd) * S_ + sbase + sc * 8) = v;
    }
  }
}

// ---- causal flash attention: Qh,Kh [bh][s][hd], VT [bh][hd][s] -> attn [b][s][h*64+hd]
__global__ __launch_bounds__(256) void attn_k(const bf16_t* __restrict__ qh,
                                              const bf16_t* __restrict__ kh,
                                              const bf16_t* __restrict__ vt,
                                              bf16_t* __restrict__ attn) {
  __shared__ bf16_t plds[4][16 * 72];  // per-wave P tile, padded (+8 bf16/row)
  const int tid = threadIdx.x, w = tid >> 6, l = tid & 63;
  const int lr = l & 15, lg = l >> 4;
  const int qt = blockIdx.x, bh = blockIdx.y;
  const int q0 = qt * 64 + w * 16;

  const bf16_t* qp = qh + ((size_t)bh * S_ + q0 + lr) * HD_ + lg * 8;
  bf16x8 qf0 = *(const bf16x8*)qp;
  bf16x8 qf1 = *(const bf16x8*)(qp + 32);

  float mi[4], li[4];
  f32x4 o[4];
#pragma unroll
  for (int r = 0; r < 4; r++) { mi[r] = -1e30f; li[r] = 0.f; }
#pragma unroll
  for (int nt = 0; nt < 4; nt++) {
    f32x4 z = {0.f, 0.f, 0.f, 0.f};
    o[nt] = z;
  }
  bf16_t* myp = plds[w];

  const int jend = qt * 64;
  for (int j0 = 0; j0 <= jend; j0 += 64) {
    f32x4 s[4];
#pragma unroll
    for (int nt = 0; nt < 4; nt++) {
      const bf16_t* kp = kh + ((size_t)bh * S_ + j0 + nt * 16 + lr) * HD_ + lg * 8;
      f32x4 a = {0.f, 0.f, 0.f, 0.f};
      a = MFMA(qf0, *(const bf16x8*)kp, a);
      a = MFMA(qf1, *(const bf16x8*)(kp + 32), a);
      s[nt] = a;
    }
    // causal mask: col j = j0+nt*16+lr, row i = q0+lg*4+r
#pragma unroll
    for (int nt = 0; nt < 4; nt++)
#pragma unroll
      for (int r = 0; r < 4; r++)
        if (j0 + nt * 16 + lr > q0 + lg * 4 + r) s[nt][r] = -1e30f;
    // online softmax: row stats live in the 16-lane group (xor 1,2,4,8)
    float mx[4];
#pragma unroll
    for (int r = 0; r < 4; r++)
      mx[r] = fmaxf(fmaxf(s[0][r], s[1][r]), fmaxf(s[2][r], s[3][r]));
#pragma unroll
    for (int d = 1; d < 16; d <<= 1) {
#pragma unroll
      for (int r = 0; r < 4; r++) mx[r] = fmaxf(mx[r], __shfl_xor(mx[r], d));
    }
    float al[4];
#pragma unroll
    for (int r = 0; r < 4; r++) {
      float mn = fmaxf(mi[r], mx[r]);
      al[r] = exp2f((mi[r] - mn) * 1.44269504088896340736f);
      mi[r] = mn;
    }
#pragma unroll
    for (int nt = 0; nt < 4; nt++)
#pragma unroll
      for (int r = 0; r < 4; r++)
        s[nt][r] = exp2f((s[nt][r] - mi[r]) * 1.44269504088896340736f);
    float rs[4];
#pragma unroll
    for (int r = 0; r < 4; r++) rs[r] = (s[0][r] + s[1][r]) + (s[2][r] + s[3][r]);
#pragma unroll
    for (int d = 1; d < 16; d <<= 1) {
#pragma unroll
      for (int r = 0; r < 4; r++) rs[r] += __shfl_xor(rs[r], d);
    }
#pragma unroll
    for (int r = 0; r < 4; r++) li[r] = li[r] * al[r] + rs[r];
#pragma unroll
    for (int nt = 0; nt < 4; nt++)
#pragma unroll
      for (int r = 0; r < 4; r++) o[nt][r] *= al[r];
    // P -> LDS (bf16), then PV
#pragma unroll
    for (int nt = 0; nt < 4; nt++)
#pragma unroll
      for (int r = 0; r < 4; r++)
        myp[(lg * 4 + r) * 72 + nt * 16 + lr] = (bf16_t)s[nt][r];
#pragma unroll
    for (int ntd = 0; ntd < 4; ntd++) {
      const bf16_t* vp = vt + ((size_t)bh * HD_ + ntd * 16 + lr) * S_ + j0 + lg * 8;
#pragma unroll
      for (int kb = 0; kb < 2; kb++) {
        bf16x8 pa = *(const bf16x8*)(myp + lr * 72 + kb * 32 + lg * 8);
        bf16x8 vf = *(const bf16x8*)(vp + kb * 32);
        o[ntd] = MFMA(pa, vf, o[ntd]);
      }
    }
  }
  // epilogue: attn[b][s][h*64+hd]
  const int b = bh >> 4, h = bh & 15;
#pragma unroll
  for (int r = 0; r < 4; r++) {
    float rinv = 1.f / li[r];
    int srow = q0 + lg * 4 + r;
#pragma unroll
    for (int ntd = 0; ntd < 4; ntd++)
      attn[((size_t)(b * S_ + srow)) * D_ + h * 64 + ntd * 16 + lr] =
          (bf16_t)(o[ntd][r] * rinv);
  }
}

extern "C" void kernel_launch(void* const* d_in, const int* in_sizes, int n_in,
                              void* d_out, int out_size, void* d_ws, size_t ws_size,
                              hipStream_t stream) {
  (void)in_sizes; (void)n_in; (void)out_size; (void)ws_size;
  const float* q  = (const float*)d_in[0];
  const float* k  = (const float*)d_in[1];
  const float* v  = (const float*)d_in[2];
  // d_in[3] = mask: causal triu, hard-coded in attn_k
  const float* Wq = (const float*)d_in[4];
  const float* bq = (const float*)d_in[5];
  const float* Wk = (const float*)d_in[6];
  const float* bk = (const float*)d_in[7];
  const float* Wv = (const float*)d_in[8];
  const float* bv = (const float*)d_in[9];
  const float* Wo = (const float*)d_in[10];
  const float* bo = (const float*)d_in[11];

  char* ws = (char*)d_ws;
  bf16_t* wtq = (bf16_t*)(ws + (0ull << 20));
  bf16_t* wtk = (bf16_t*)(ws + (2ull << 20));
  bf16_t* wtv = (bf16_t*)(ws + (4ull << 20));
  bf16_t* wto = (bf16_t*)(ws + (6ull << 20));
  bf16_t* qhb = (bf16_t*)(ws + (8ull << 20));
  bf16_t* khb = (bf16_t*)(ws + (24ull << 20));
  bf16_t* vtb = (bf16_t*)(ws + (40ull << 20));
  bf16_t* atb = (bf16_t*)(ws + (56ull << 20));

  dim3 tb(256);
  wt_kernel<<<dim3(32, 32), tb, 0, stream>>>(Wq, wtq);
  wt_kernel<<<dim3(32, 32), tb, 0, stream>>>(Wk, wtk);
  wt_kernel<<<dim3(32, 32), tb, 0, stream>>>(Wv, wtv);
  wt_kernel<<<dim3(32, 32), tb, 0, stream>>>(Wo, wto);

  dim3 gg(8, 64);  // N/128, M/128
  gemm_k<0><<<gg, tb, 0, stream>>>(q, wtq, bq, qhb);
  gemm_k<1><<<gg, tb, 0, stream>>>(k, wtk, bk, khb);
  gemm_k<2><<<gg, tb, 0, stream>>>(v, wtv, bv, vtb);

  attn_k<<<dim3(32, 64), tb, 0, stream>>>(qhb, khb, vtb, atb);

  gemm_k<3><<<gg, tb, 0, stream>>>(atb, wto, bo, d_out);
}

// Round 2
// 288.225 us; speedup vs baseline: 2.1357x; 2.1357x over previous
//
#include <hip/hip_runtime.h>
#include <hip/hip_bf16.h>
#include <stdint.h>

#define B_ 4
#define S_ 2048
#define D_ 1024
#define H_ 16
#define HD_ 64

typedef __bf16 bf16_t;
typedef __bf16 bf16x8 __attribute__((ext_vector_type(8)));
typedef float f32x4 __attribute__((ext_vector_type(4)));

#define MFMA(a, b, c) __builtin_amdgcn_mfma_f32_16x16x32_bf16((a), (b), (c), 0, 0, 0)

__device__ __forceinline__ void gload_lds16(const void* g, void* l) {
  __builtin_amdgcn_global_load_lds(
      (const __attribute__((address_space(1))) uint32_t*)g,
      (__attribute__((address_space(3))) uint32_t*)l, 16, 0, 0);
}

// ---- weight transpose + convert: WT[n][k] = bf16(W[k][n]) -------------------
__global__ __launch_bounds__(256) void wt_kernel(const float* __restrict__ w,
                                                 bf16_t* __restrict__ wt) {
  __shared__ float t[32][33];
  const int tx = threadIdx.x & 31, ty = threadIdx.x >> 5;
  const int n0 = blockIdx.x * 32, k0 = blockIdx.y * 32;
#pragma unroll
  for (int i = 0; i < 4; i++)
    t[ty + i * 8][tx] = w[(size_t)(k0 + ty + i * 8) * D_ + n0 + tx];
  __syncthreads();
#pragma unroll
  for (int i = 0; i < 4; i++)
    wt[(size_t)(n0 + ty + i * 8) * D_ + k0 + tx] = (bf16_t)t[tx][ty + i * 8];
}

// ---- GEMM: C[8192x1024] = A[8192x1024] @ W + b ------------------------------
// MODE 0: A=f32 q,  out = bf16 Qh[(b*16+h)][s][hd] * 0.125
// MODE 1: A=f32 k,  out = bf16 Kh[(b*16+h)][s][hd]
// MODE 2: A=f32 v,  out = bf16 VT[(b*16+h)][hd][s]   (LDS-transposed epilogue)
// MODE 3: A=bf16 attn, out = f32 [m][n] + bias
template <int MODE>
__global__ __launch_bounds__(256) void gemm_k(const void* __restrict__ Av,
                                              const bf16_t* __restrict__ WT,
                                              const float* __restrict__ bias,
                                              void* __restrict__ Ov) {
  constexpr int K = D_;
  __shared__ bf16_t smem[17408];  // staging: A[128][64] + B[128][64]; MODE2 epi: [128][136]
  bf16_t* alds = smem;
  bf16_t* blds = smem + 8192;

  const int tid = threadIdx.x;
  const int w = tid >> 6, l = tid & 63;
  const int lr = l & 15, lg = l >> 4;
  const int wm = w >> 1, wn = w & 1;
  const int m0 = blockIdx.y * 128, n0 = blockIdx.x * 128;

  f32x4 acc[4][4];
#pragma unroll
  for (int mt = 0; mt < 4; mt++)
#pragma unroll
    for (int nt = 0; nt < 4; nt++) {
      f32x4 z = {0.f, 0.f, 0.f, 0.f};
      acc[mt][nt] = z;
    }

  for (int k0 = 0; k0 < K; k0 += 64) {
    // stage B tile (WT rows = n), swizzled source -> linear LDS
#pragma unroll
    for (int c = 0; c < 4; c++) {
      int ci = c * 256 + w * 64 + l;
      int row = ci >> 3, kc = ci & 7;
      int ks = kc ^ (row & 7);
      gload_lds16(WT + (size_t)(n0 + row) * K + k0 + ks * 8,
                  blds + (size_t)(c * 256 + w * 64) * 8);
    }
    // stage A tile
    if constexpr (MODE != 3) {
      const float* A = (const float*)Av;
#pragma unroll
      for (int c = 0; c < 4; c++) {
        int ci = c * 256 + tid;
        int row = ci >> 3, kc = ci & 7;
        int ks = kc ^ (row & 7);
        const float* src = A + (size_t)(m0 + row) * K + k0 + ks * 8;
        float4 x0 = ((const float4*)src)[0];
        float4 x1 = ((const float4*)src)[1];
        bf16x8 vv;
        vv[0] = (bf16_t)x0.x; vv[1] = (bf16_t)x0.y; vv[2] = (bf16_t)x0.z; vv[3] = (bf16_t)x0.w;
        vv[4] = (bf16_t)x1.x; vv[5] = (bf16_t)x1.y; vv[6] = (bf16_t)x1.z; vv[7] = (bf16_t)x1.w;
        *reinterpret_cast<bf16x8*>(alds + (size_t)ci * 8) = vv;
      }
    } else {
      const bf16_t* A = (const bf16_t*)Av;
#pragma unroll
      for (int c = 0; c < 4; c++) {
        int ci = c * 256 + w * 64 + l;
        int row = ci >> 3, kc = ci & 7;
        int ks = kc ^ (row & 7);
        gload_lds16(A + (size_t)(m0 + row) * K + k0 + ks * 8,
                    alds + (size_t)(c * 256 + w * 64) * 8);
      }
    }
    __syncthreads();
#pragma unroll
    for (int kk = 0; kk < 2; kk++) {
      bf16x8 af[4], bfr[4];
#pragma unroll
      for (int mt = 0; mt < 4; mt++) {
        int row = wm * 64 + mt * 16 + lr;
        int kc = kk * 4 + lg;
        af[mt] = *reinterpret_cast<const bf16x8*>(alds + row * 64 + ((kc ^ (row & 7)) * 8));
      }
#pragma unroll
      for (int nt = 0; nt < 4; nt++) {
        int row = wn * 64 + nt * 16 + lr;
        int kc = kk * 4 + lg;
        bfr[nt] = *reinterpret_cast<const bf16x8*>(blds + row * 64 + ((kc ^ (row & 7)) * 8));
      }
#pragma unroll
      for (int mt = 0; mt < 4; mt++)
#pragma unroll
        for (int nt = 0; nt < 4; nt++)
          acc[mt][nt] = MFMA(af[mt], bfr[nt], acc[mt][nt]);
    }
    __syncthreads();
  }

  float bn[4];
#pragma unroll
  for (int nt = 0; nt < 4; nt++) bn[nt] = bias[n0 + wn * 64 + nt * 16 + lr];

  if constexpr (MODE == 0 || MODE == 1) {
    bf16_t* out = (bf16_t*)Ov;
#pragma unroll
    for (int mt = 0; mt < 4; mt++)
#pragma unroll
      for (int nt = 0; nt < 4; nt++)
#pragma unroll
        for (int r = 0; r < 4; r++) {
          int m = m0 + wm * 64 + mt * 16 + lg * 4 + r;
          int n = n0 + wn * 64 + nt * 16 + lr;
          float v = acc[mt][nt][r] + bn[nt];
          if constexpr (MODE == 0) v *= 0.125f;  // 1/sqrt(HD), exact in bf16
          int b = m >> 11, s = m & 2047, h = n >> 6, hd = n & 63;
          out[(((size_t)(b * H_ + h) * S_ + s) << 6) + hd] = (bf16_t)v;
        }
  } else if constexpr (MODE == 3) {
    float* out = (float*)Ov;
#pragma unroll
    for (int mt = 0; mt < 4; mt++)
#pragma unroll
      for (int nt = 0; nt < 4; nt++)
#pragma unroll
        for (int r = 0; r < 4; r++) {
          int m = m0 + wm * 64 + mt * 16 + lg * 4 + r;
          int n = n0 + wn * 64 + nt * 16 + lr;
          out[(size_t)m * D_ + n] = acc[mt][nt][r] + bn[nt];
        }
  } else {  // MODE 2: transpose in LDS, write VT[(b*16+h)][hd][s]
    __syncthreads();
#pragma unroll
    for (int mt = 0; mt < 4; mt++)
#pragma unroll
      for (int nt = 0; nt < 4; nt++)
#pragma unroll
        for (int r = 0; r < 4; r++) {
          int ml = wm * 64 + mt * 16 + lg * 4 + r;
          int nl = wn * 64 + nt * 16 + lr;
          smem[nl * 136 + ml] = (bf16_t)(acc[mt][nt][r] + bn[nt]);
        }
    __syncthreads();
    bf16_t* out = (bf16_t*)Ov;
    const int b = m0 >> 11, sbase = m0 & 2047;
#pragma unroll
    for (int c = 0; c < 8; c++) {
      int ci = c * 256 + tid;
      int dl = ci >> 4, sc = ci & 15;
      int n = n0 + dl, h = n >> 6, hd = n & 63;
      bf16x8 v = *reinterpret_cast<const bf16x8*>(smem + dl * 136 + sc * 8);
      *reinterpret_cast<bf16x8*>(out + ((size_t)((b * H_ + h) << 6) + hd) * S_ + sbase + sc * 8) = v;
    }
  }
}

// ---- causal flash attention ------------------------------------------------
// Qh,Kh [bh][s][hd], VT [bh][hd][s] -> attn [b][s][h*64+hd]
// 512 threads = 8 waves; 128 Q-rows per q-tile (wave w owns rows w*16..+15).
// Block x processes q-tiles {x, 15-x}: uniform 34 kv-tile iterations/block.
// K/V 64x64 tiles double-buffered in LDS via global_load_lds (swizzled source,
// linear LDS dest, swizzled ds_read — rule #21).
__global__ __launch_bounds__(512) void attn_k(const bf16_t* __restrict__ qh,
                                              const bf16_t* __restrict__ kh,
                                              const bf16_t* __restrict__ vt,
                                              bf16_t* __restrict__ attn) {
  __shared__ bf16_t kbuf[2][4096];
  __shared__ bf16_t vbuf[2][4096];
  __shared__ bf16_t plds[8][16 * 72];  // per-wave P tile, padded (+8 bf16/row)

  const int tid = threadIdx.x, w = tid >> 6, l = tid & 63;
  const int lr = l & 15, lg = l >> 4;
  const int bh = blockIdx.y;
  const int b = bh >> 4, h = bh & 15;

  // staging geometry: thread -> (row 0..63, 16B chunk), source pre-swizzled
  const int srow = tid >> 3;
  const int sks = (tid & 7) ^ (srow & 7);
  const bf16_t* ksrc0 = kh + ((size_t)bh * S_ + srow) * HD_ + sks * 8;
  const bf16_t* vsrc0 = vt + ((size_t)bh * HD_ + srow) * S_ + sks * 8;
  const int soff = w * 512;  // wave-uniform LDS element offset
  bf16_t* myp = plds[w];
  const int xs7 = lr & 7;  // read-side swizzle key (row&7 == lr&7 for all frags)

  for (int half = 0; half < 2; half++) {
    const int qt = half ? (15 - (int)blockIdx.x) : (int)blockIdx.x;
    const int q0 = qt * 128 + w * 16;
    const int jend = qt * 128 + 64;

    const bf16_t* qp = qh + ((size_t)bh * S_ + q0 + lr) * HD_ + lg * 8;
    bf16x8 qf0 = *(const bf16x8*)qp;
    bf16x8 qf1 = *(const bf16x8*)(qp + 32);

    float mi[4], li[4];
    f32x4 o[4];
#pragma unroll
    for (int r = 0; r < 4; r++) { mi[r] = -1e30f; li[r] = 0.f; }
#pragma unroll
    for (int nt = 0; nt < 4; nt++) {
      f32x4 z = {0.f, 0.f, 0.f, 0.f};
      o[nt] = z;
    }

    // prologue: stage tile 0
    gload_lds16(ksrc0, kbuf[0] + soff);
    gload_lds16(vsrc0, vbuf[0] + soff);
    __syncthreads();

    int cur = 0;
    for (int j0 = 0; j0 <= jend; j0 += 64) {
      if (j0 + 64 <= jend) {  // issue next-tile stage before compute
        gload_lds16(ksrc0 + (size_t)(j0 + 64) * HD_, kbuf[cur ^ 1] + soff);
        gload_lds16(vsrc0 + (j0 + 64), vbuf[cur ^ 1] + soff);
      }
      if (j0 <= q0 + 15) {  // wave-uniform: skip fully-masked tiles
        const bf16_t* kt = kbuf[cur];
        const bf16_t* vb = vbuf[cur];
        f32x4 s[4];
#pragma unroll
        for (int nt = 0; nt < 4; nt++) {
          const bf16_t* kp = kt + (nt * 16 + lr) * 64;
          bf16x8 k0 = *(const bf16x8*)(kp + ((lg ^ xs7) * 8));
          bf16x8 k1 = *(const bf16x8*)(kp + (((4 + lg) ^ xs7) * 8));
          f32x4 a = {0.f, 0.f, 0.f, 0.f};
          a = MFMA(qf0, k0, a);
          a = MFMA(qf1, k1, a);
          s[nt] = a;
        }
        if (j0 + 63 > q0) {  // diagonal tiles: apply causal mask
#pragma unroll
          for (int nt = 0; nt < 4; nt++)
#pragma unroll
            for (int r = 0; r < 4; r++)
              if (j0 + nt * 16 + lr > q0 + lg * 4 + r) s[nt][r] = -1e30f;
        }
        // online softmax: row stats in the 16-lane group
        float mx[4];
#pragma unroll
        for (int r = 0; r < 4; r++)
          mx[r] = fmaxf(fmaxf(s[0][r], s[1][r]), fmaxf(s[2][r], s[3][r]));
#pragma unroll
        for (int d = 1; d < 16; d <<= 1) {
#pragma unroll
          for (int r = 0; r < 4; r++) mx[r] = fmaxf(mx[r], __shfl_xor(mx[r], d));
        }
        float al[4];
#pragma unroll
        for (int r = 0; r < 4; r++) {
          float mn = fmaxf(mi[r], mx[r]);
          al[r] = exp2f((mi[r] - mn) * 1.44269504088896340736f);
          mi[r] = mn;
        }
#pragma unroll
        for (int nt = 0; nt < 4; nt++)
#pragma unroll
          for (int r = 0; r < 4; r++)
            s[nt][r] = exp2f((s[nt][r] - mi[r]) * 1.44269504088896340736f);
        float rs[4];
#pragma unroll
        for (int r = 0; r < 4; r++) rs[r] = (s[0][r] + s[1][r]) + (s[2][r] + s[3][r]);
#pragma unroll
        for (int d = 1; d < 16; d <<= 1) {
#pragma unroll
          for (int r = 0; r < 4; r++) rs[r] += __shfl_xor(rs[r], d);
        }
#pragma unroll
        for (int r = 0; r < 4; r++) li[r] = li[r] * al[r] + rs[r];
#pragma unroll
        for (int nt = 0; nt < 4; nt++)
#pragma unroll
          for (int r = 0; r < 4; r++) o[nt][r] *= al[r];
        // P -> LDS (bf16), then PV from staged V
#pragma unroll
        for (int nt = 0; nt < 4; nt++)
#pragma unroll
          for (int r = 0; r < 4; r++)
            myp[(lg * 4 + r) * 72 + nt * 16 + lr] = (bf16_t)s[nt][r];
#pragma unroll
        for (int ntd = 0; ntd < 4; ntd++) {
          const bf16_t* vp = vb + (ntd * 16 + lr) * 64;
#pragma unroll
          for (int kb2 = 0; kb2 < 2; kb2++) {
            bf16x8 pa = *(const bf16x8*)(myp + lr * 72 + kb2 * 32 + lg * 8);
            bf16x8 vf = *(const bf16x8*)(vp + (((kb2 * 4 + lg) ^ xs7) * 8));
            o[ntd] = MFMA(pa, vf, o[ntd]);
          }
        }
      }
      __syncthreads();  // staged loads drained (vmcnt) + buffer reads done
      cur ^= 1;
    }
    // epilogue: attn[b][s][h*64+hd]
#pragma unroll
    for (int r = 0; r < 4; r++) {
      float rinv = 1.f / li[r];
      int srw = q0 + lg * 4 + r;
#pragma unroll
      for (int ntd = 0; ntd < 4; ntd++)
        attn[((size_t)(b * S_ + srw)) * D_ + h * 64 + ntd * 16 + lr] =
            (bf16_t)(o[ntd][r] * rinv);
    }
  }
}

extern "C" void kernel_launch(void* const* d_in, const int* in_sizes, int n_in,
                              void* d_out, int out_size, void* d_ws, size_t ws_size,
                              hipStream_t stream) {
  (void)in_sizes; (void)n_in; (void)out_size; (void)ws_size;
  const float* q  = (const float*)d_in[0];
  const float* k  = (const float*)d_in[1];
  const float* v  = (const float*)d_in[2];
  // d_in[3] = mask: causal triu, hard-coded in attn_k
  const float* Wq = (const float*)d_in[4];
  const float* bq = (const float*)d_in[5];
  const float* Wk = (const float*)d_in[6];
  const float* bk = (const float*)d_in[7];
  const float* Wv = (const float*)d_in[8];
  const float* bv = (const float*)d_in[9];
  const float* Wo = (const float*)d_in[10];
  const float* bo = (const float*)d_in[11];

  char* ws = (char*)d_ws;
  bf16_t* wtq = (bf16_t*)(ws + (0ull << 20));
  bf16_t* wtk = (bf16_t*)(ws + (2ull << 20));
  bf16_t* wtv = (bf16_t*)(ws + (4ull << 20));
  bf16_t* wto = (bf16_t*)(ws + (6ull << 20));
  bf16_t* qhb = (bf16_t*)(ws + (8ull << 20));
  bf16_t* khb = (bf16_t*)(ws + (24ull << 20));
  bf16_t* vtb = (bf16_t*)(ws + (40ull << 20));
  bf16_t* atb = (bf16_t*)(ws + (56ull << 20));

  dim3 tb(256);
  wt_kernel<<<dim3(32, 32), tb, 0, stream>>>(Wq, wtq);
  wt_kernel<<<dim3(32, 32), tb, 0, stream>>>(Wk, wtk);
  wt_kernel<<<dim3(32, 32), tb, 0, stream>>>(Wv, wtv);
  wt_kernel<<<dim3(32, 32), tb, 0, stream>>>(Wo, wto);

  dim3 gg(8, 64);  // N/128, M/128
  gemm_k<0><<<gg, tb, 0, stream>>>(q, wtq, bq, qhb);
  gemm_k<1><<<gg, tb, 0, stream>>>(k, wtk, bk, khb);
  gemm_k<2><<<gg, tb, 0, stream>>>(v, wtv, bv, vtb);

  attn_k<<<dim3(8, 64), dim3(512), 0, stream>>>(qhb, khb, vtb, atb);

  gemm_k<3><<<gg, tb, 0, stream>>>(atb, wto, bo, d_out);
}

// Round 3
// 200.445 us; speedup vs baseline: 3.0710x; 1.4379x over previous
//
#include <hip/hip_runtime.h>
#include <hip/hip_bf16.h>
#include <stdint.h>

#define B_ 4
#define S_ 2048
#define D_ 1024
#define H_ 16
#define HD_ 64

typedef __bf16 bf16_t;
typedef __bf16 bf16x8 __attribute__((ext_vector_type(8)));
typedef __bf16 bf16x2_t __attribute__((ext_vector_type(2)));
typedef float f32x4 __attribute__((ext_vector_type(4)));
typedef int i32x4 __attribute__((ext_vector_type(4)));

#define MFMA(a, b, c) __builtin_amdgcn_mfma_f32_16x16x32_bf16((a), (b), (c), 0, 0, 0)
#define LOG2E 1.44269504088896340736f

__device__ __forceinline__ void gload_lds16(const void* g, void* l) {
  __builtin_amdgcn_global_load_lds(
      (const __attribute__((address_space(1))) uint32_t*)g,
      (__attribute__((address_space(3))) uint32_t*)l, 16, 0, 0);
}

// ---- weight transpose + convert: WT[n][k] = bf16(W[k][n]) -------------------
__global__ __launch_bounds__(256) void wt_kernel(const float* __restrict__ w,
                                                 bf16_t* __restrict__ wt) {
  __shared__ float t[32][33];
  const int tx = threadIdx.x & 31, ty = threadIdx.x >> 5;
  const int n0 = blockIdx.x * 32, k0 = blockIdx.y * 32;
#pragma unroll
  for (int i = 0; i < 4; i++)
    t[ty + i * 8][tx] = w[(size_t)(k0 + ty + i * 8) * D_ + n0 + tx];
  __syncthreads();
#pragma unroll
  for (int i = 0; i < 4; i++)
    wt[(size_t)(n0 + ty + i * 8) * D_ + k0 + tx] = (bf16_t)t[tx][ty + i * 8];
}

// ---- GEMM: C[8192x1024] = A[8192x1024] @ W + b ------------------------------
// MODE 0: A=f32 q,  out = bf16 Qh[(b*16+h)][s][hd] * 0.125
// MODE 1: A=f32 k,  out = bf16 Kh[(b*16+h)][s][hd]
// MODE 2: A=f32 v,  out = bf16 VT[(b*16+h)][hd][s]   (LDS-transposed epilogue)
// MODE 3: A=bf16 attn, out = f32 [m][n] + bias
template <int MODE>
__global__ __launch_bounds__(256) void gemm_k(const void* __restrict__ Av,
                                              const bf16_t* __restrict__ WT,
                                              const float* __restrict__ bias,
                                              void* __restrict__ Ov) {
  constexpr int K = D_;
  __shared__ bf16_t smem[17408];  // staging: A[128][64] + B[128][64]; MODE2 epi: [128][136]
  bf16_t* alds = smem;
  bf16_t* blds = smem + 8192;

  const int tid = threadIdx.x;
  const int w = tid >> 6, l = tid & 63;
  const int lr = l & 15, lg = l >> 4;
  const int wm = w >> 1, wn = w & 1;
  // XCD-chunked swizzle: 8 consecutive hw blocks (one per XCD) -> 8 m-panels;
  // each XCD sees 8 contiguous m-panels (4 MB A) reused across all 8 n-blocks.
  const int ib = (int)blockIdx.y * (int)gridDim.x + (int)blockIdx.x;  // 512 blocks
  const int swz = (ib & 7) * 64 + (ib >> 3);
  const int m0 = (swz >> 3) * 128, n0 = (swz & 7) * 128;

  f32x4 acc[4][4];
#pragma unroll
  for (int mt = 0; mt < 4; mt++)
#pragma unroll
    for (int nt = 0; nt < 4; nt++) {
      f32x4 z = {0.f, 0.f, 0.f, 0.f};
      acc[mt][nt] = z;
    }

  for (int k0 = 0; k0 < K; k0 += 64) {
    // stage B tile (WT rows = n), swizzled source -> linear LDS
#pragma unroll
    for (int c = 0; c < 4; c++) {
      int ci = c * 256 + w * 64 + l;
      int row = ci >> 3, kc = ci & 7;
      int ks = kc ^ (row & 7);
      gload_lds16(WT + (size_t)(n0 + row) * K + k0 + ks * 8,
                  blds + (size_t)(c * 256 + w * 64) * 8);
    }
    // stage A tile
    if constexpr (MODE != 3) {
      const float* A = (const float*)Av;
#pragma unroll
      for (int c = 0; c < 4; c++) {
        int ci = c * 256 + tid;
        int row = ci >> 3, kc = ci & 7;
        int ks = kc ^ (row & 7);
        const float* src = A + (size_t)(m0 + row) * K + k0 + ks * 8;
        float4 x0 = ((const float4*)src)[0];
        float4 x1 = ((const float4*)src)[1];
        bf16x8 vv;
        vv[0] = (bf16_t)x0.x; vv[1] = (bf16_t)x0.y; vv[2] = (bf16_t)x0.z; vv[3] = (bf16_t)x0.w;
        vv[4] = (bf16_t)x1.x; vv[5] = (bf16_t)x1.y; vv[6] = (bf16_t)x1.z; vv[7] = (bf16_t)x1.w;
        *reinterpret_cast<bf16x8*>(alds + (size_t)ci * 8) = vv;
      }
    } else {
      const bf16_t* A = (const bf16_t*)Av;
#pragma unroll
      for (int c = 0; c < 4; c++) {
        int ci = c * 256 + w * 64 + l;
        int row = ci >> 3, kc = ci & 7;
        int ks = kc ^ (row & 7);
        gload_lds16(A + (size_t)(m0 + row) * K + k0 + ks * 8,
                    alds + (size_t)(c * 256 + w * 64) * 8);
      }
    }
    __syncthreads();
#pragma unroll
    for (int kk = 0; kk < 2; kk++) {
      bf16x8 af[4], bfr[4];
#pragma unroll
      for (int mt = 0; mt < 4; mt++) {
        int row = wm * 64 + mt * 16 + lr;
        int kc = kk * 4 + lg;
        af[mt] = *reinterpret_cast<const bf16x8*>(alds + row * 64 + ((kc ^ (row & 7)) * 8));
      }
#pragma unroll
      for (int nt = 0; nt < 4; nt++) {
        int row = wn * 64 + nt * 16 + lr;
        int kc = kk * 4 + lg;
        bfr[nt] = *reinterpret_cast<const bf16x8*>(blds + row * 64 + ((kc ^ (row & 7)) * 8));
      }
#pragma unroll
      for (int mt = 0; mt < 4; mt++)
#pragma unroll
        for (int nt = 0; nt < 4; nt++)
          acc[mt][nt] = MFMA(af[mt], bfr[nt], acc[mt][nt]);
    }
    __syncthreads();
  }

  float bn[4];
#pragma unroll
  for (int nt = 0; nt < 4; nt++) bn[nt] = bias[n0 + wn * 64 + nt * 16 + lr];

  if constexpr (MODE == 0 || MODE == 1) {
    bf16_t* out = (bf16_t*)Ov;
#pragma unroll
    for (int mt = 0; mt < 4; mt++)
#pragma unroll
      for (int nt = 0; nt < 4; nt++)
#pragma unroll
        for (int r = 0; r < 4; r++) {
          int m = m0 + wm * 64 + mt * 16 + lg * 4 + r;
          int n = n0 + wn * 64 + nt * 16 + lr;
          float v = acc[mt][nt][r] + bn[nt];
          if constexpr (MODE == 0) v *= 0.125f;  // 1/sqrt(HD), exact in bf16
          int b = m >> 11, s = m & 2047, h = n >> 6, hd = n & 63;
          out[(((size_t)(b * H_ + h) * S_ + s) << 6) + hd] = (bf16_t)v;
        }
  } else if constexpr (MODE == 3) {
    float* out = (float*)Ov;
#pragma unroll
    for (int mt = 0; mt < 4; mt++)
#pragma unroll
      for (int nt = 0; nt < 4; nt++)
#pragma unroll
        for (int r = 0; r < 4; r++) {
          int m = m0 + wm * 64 + mt * 16 + lg * 4 + r;
          int n = n0 + wn * 64 + nt * 16 + lr;
          out[(size_t)m * D_ + n] = acc[mt][nt][r] + bn[nt];
        }
  } else {  // MODE 2: transpose in LDS, write VT[(b*16+h)][hd][s]
    __syncthreads();
#pragma unroll
    for (int mt = 0; mt < 4; mt++)
#pragma unroll
      for (int nt = 0; nt < 4; nt++)
#pragma unroll
        for (int r = 0; r < 4; r++) {
          int ml = wm * 64 + mt * 16 + lg * 4 + r;
          int nl = wn * 64 + nt * 16 + lr;
          smem[nl * 136 + ml] = (bf16_t)(acc[mt][nt][r] + bn[nt]);
        }
    __syncthreads();
    bf16_t* out = (bf16_t*)Ov;
    const int b = m0 >> 11, sbase = m0 & 2047;
#pragma unroll
    for (int c = 0; c < 8; c++) {
      int ci = c * 256 + tid;
      int dl = ci >> 4, sc = ci & 15;
      int n = n0 + dl, h = n >> 6, hd = n & 63;
      bf16x8 v = *reinterpret_cast<const bf16x8*>(smem + dl * 136 + sc * 8);
      *reinterpret_cast<bf16x8*>(out + ((size_t)((b * H_ + h) << 6) + hd) * S_ + sbase + sc * 8) = v;
    }
  }
}

// ---- causal flash attention ------------------------------------------------
// Qh,Kh [bh][s][hd], VT [bh][hd][s] -> attn [b][s][h*64+hd]
// Swapped QK^T (MFMA(K,Q)): each lane holds one q-row (lr) x 16 kv values.
// K rows are bit-permuted in LDS (pi(z)=(z5,z3,z2,z4,z1,z0)) so the S^T output
// per lane IS the PV A-fragment kv ordering: P->PA = 8 bf16 packs, no shuffles.
// li accumulated via ones-column MFMA (os). T13 defer-max; T5 setprio.
__global__ __launch_bounds__(512) void attn_k(const bf16_t* __restrict__ qh,
                                              const bf16_t* __restrict__ kh,
                                              const bf16_t* __restrict__ vt,
                                              bf16_t* __restrict__ attn) {
  __shared__ bf16_t kbuf[2][4096];
  __shared__ bf16_t vbuf[2][4096];

  const int tid = threadIdx.x, w = tid >> 6, l = tid & 63;
  const int lr = l & 15, lg = l >> 4;

  // XCD swizzle: the 8 q-tile-pair blocks of one bh land on one XCD (K/V L2-resident)
  const int ib = (int)blockIdx.y * 8 + (int)blockIdx.x;  // 512 blocks
  const int bh = (ib & 7) * 8 + (ib >> 6);
  const int xq = (ib >> 3) & 7;
  const int b = bh >> 4, h = bh & 15;

  // staging: LDS slot-row zr holds K global row pi(zr); columns xor-swizzled
  const int zr = tid >> 3;
  const int sks = (tid & 7) ^ (zr & 7);
  const int kprow = ((zr >> 5) & 1) * 32 + ((zr >> 2) & 3) * 8 + ((zr >> 4) & 1) * 4 + (zr & 3);
  const bf16_t* ksrc0 = kh + ((size_t)bh * S_ + kprow) * HD_ + sks * 8;
  const bf16_t* vsrc0 = vt + ((size_t)bh * HD_ + zr) * S_ + sks * 8;
  const int soff = w * 512;  // wave-uniform LDS element offset
  const int xs7 = lr & 7;    // read-side swizzle key

  bf16x8 ones;
#pragma unroll
  for (int i = 0; i < 8; i++) ones[i] = (bf16_t)1.0f;

  for (int half = 0; half < 2; half++) {
    const int qt = half ? (15 - xq) : xq;
    const int q0 = qt * 128 + w * 16;
    const int jend = qt * 128 + 64;

    const bf16_t* qp = qh + ((size_t)bh * S_ + q0 + lr) * HD_ + lg * 8;
    bf16x8 qf0 = *(const bf16x8*)qp;
    bf16x8 qf1 = *(const bf16x8*)(qp + 32);

    float mi = -1e30f;
    f32x4 o[4], os;
#pragma unroll
    for (int nt = 0; nt < 4; nt++) {
      f32x4 z = {0.f, 0.f, 0.f, 0.f};
      o[nt] = z;
    }
    {
      f32x4 z = {0.f, 0.f, 0.f, 0.f};
      os = z;
    }

    // prologue: stage tile 0
    gload_lds16(ksrc0, kbuf[0] + soff);
    gload_lds16(vsrc0, vbuf[0] + soff);
    __syncthreads();

    int cur = 0;
    for (int j0 = 0; j0 <= jend; j0 += 64) {
      if (j0 + 64 <= jend) {  // issue next-tile stage before compute
        gload_lds16(ksrc0 + (size_t)(j0 + 64) * HD_, kbuf[cur ^ 1] + soff);
        gload_lds16(vsrc0 + (j0 + 64), vbuf[cur ^ 1] + soff);
      }
      if (j0 <= q0 + 15) {  // wave-uniform: skip fully-masked tiles
        const bf16_t* kt = kbuf[cur];
        const bf16_t* vb = vbuf[cur];
        f32x4 s[4];
        __builtin_amdgcn_s_setprio(1);
#pragma unroll
        for (int nt = 0; nt < 4; nt++) {
          const bf16_t* kp = kt + (nt * 16 + lr) * 64;
          bf16x8 kf0 = *(const bf16x8*)(kp + ((lg ^ xs7) * 8));
          bf16x8 kf1 = *(const bf16x8*)(kp + (((4 + lg) ^ xs7) * 8));
          f32x4 a = {0.f, 0.f, 0.f, 0.f};
          a = MFMA(kf0, qf0, a);   // swapped: K as A-operand
          a = MFMA(kf1, qf1, a);
          s[nt] = a;
        }
        __builtin_amdgcn_s_setprio(0);
        // causal mask: kv = j0 + pi(nt*16+lg*4+r), q-row = q0+lr
        if (j0 + 63 > q0) {
#pragma unroll
          for (int nt = 0; nt < 4; nt++) {
            int kvb = j0 + ((nt >> 1) << 5) + ((nt & 1) << 2) + lg * 8;
#pragma unroll
            for (int r = 0; r < 4; r++)
              if (kvb + r > q0 + lr) s[nt][r] = -1e30f;
          }
        }
        // row max: in-lane tree over 16 + cross-copy reduce (xor16, xor32)
        float mx0 = fmaxf(fmaxf(s[0][0], s[0][1]), fmaxf(s[0][2], s[0][3]));
        float mx1 = fmaxf(fmaxf(s[1][0], s[1][1]), fmaxf(s[1][2], s[1][3]));
        float mx2 = fmaxf(fmaxf(s[2][0], s[2][1]), fmaxf(s[2][2], s[2][3]));
        float mx3 = fmaxf(fmaxf(s[3][0], s[3][1]), fmaxf(s[3][2], s[3][3]));
        float mx = fmaxf(fmaxf(mx0, mx1), fmaxf(mx2, mx3));
        mx = fmaxf(mx, __shfl_xor(mx, 16));
        mx = fmaxf(mx, __shfl_xor(mx, 32));
        // T13 defer-max: rescale only when max grew past threshold
        if (!__all(mx <= mi + 8.0f)) {
          float mn = fmaxf(mi, mx);
          float al = exp2f((mi - mn) * LOG2E);
          mi = mn;
#pragma unroll
          for (int r = 0; r < 4; r++) {
            float alr = __shfl(al, lg * 4 + r);  // al of o's q-row (lg*4+r)
            o[0][r] *= alr; o[1][r] *= alr; o[2][r] *= alr; o[3][r] *= alr;
            os[r] *= alr;
          }
        }
        const float msc = mi * LOG2E;
#pragma unroll
        for (int nt = 0; nt < 4; nt++)
#pragma unroll
          for (int r = 0; r < 4; r++)
            s[nt][r] = exp2f(s[nt][r] * LOG2E - msc);
        // P -> PA fragments: pure in-lane packs (kv order matches by construction)
        uint32_t pk[8];
#pragma unroll
        for (int nt = 0; nt < 4; nt++) {
          bf16x2_t plo = {(bf16_t)s[nt][0], (bf16_t)s[nt][1]};
          bf16x2_t phi = {(bf16_t)s[nt][2], (bf16_t)s[nt][3]};
          pk[nt * 2] = __builtin_bit_cast(uint32_t, plo);
          pk[nt * 2 + 1] = __builtin_bit_cast(uint32_t, phi);
        }
        i32x4 w0 = {(int)pk[0], (int)pk[1], (int)pk[2], (int)pk[3]};
        i32x4 w1 = {(int)pk[4], (int)pk[5], (int)pk[6], (int)pk[7]};
        bf16x8 pa0 = __builtin_bit_cast(bf16x8, w0);
        bf16x8 pa1 = __builtin_bit_cast(bf16x8, w1);
        __builtin_amdgcn_s_setprio(1);
#pragma unroll
        for (int ntd = 0; ntd < 4; ntd++) {
          const bf16_t* vp = vb + (ntd * 16 + lr) * 64;
          bf16x8 vf0 = *(const bf16x8*)(vp + ((lg ^ xs7) * 8));
          bf16x8 vf1 = *(const bf16x8*)(vp + (((4 + lg) ^ xs7) * 8));
          o[ntd] = MFMA(pa0, vf0, o[ntd]);
          o[ntd] = MFMA(pa1, vf1, o[ntd]);
        }
        os = MFMA(pa0, ones, os);  // row-sum of P accumulates li in o-layout
        os = MFMA(pa1, ones, os);
        __builtin_amdgcn_s_setprio(0);
      }
      __syncthreads();  // staged loads drained + buffer reads done
      cur ^= 1;
    }
    // epilogue: attn[b][s][h*64+hd]
#pragma unroll
    for (int r = 0; r < 4; r++) {
      float rinv = 1.f / os[r];
      int srw = q0 + lg * 4 + r;
#pragma unroll
      for (int ntd = 0; ntd < 4; ntd++)
        attn[((size_t)(b * S_ + srw)) * D_ + h * 64 + ntd * 16 + lr] =
            (bf16_t)(o[ntd][r] * rinv);
    }
  }
}

extern "C" void kernel_launch(void* const* d_in, const int* in_sizes, int n_in,
                              void* d_out, int out_size, void* d_ws, size_t ws_size,
                              hipStream_t stream) {
  (void)in_sizes; (void)n_in; (void)out_size; (void)ws_size;
  const float* q  = (const float*)d_in[0];
  const float* k  = (const float*)d_in[1];
  const float* v  = (const float*)d_in[2];
  // d_in[3] = mask: causal triu, hard-coded in attn_k
  const float* Wq = (const float*)d_in[4];
  const float* bq = (const float*)d_in[5];
  const float* Wk = (const float*)d_in[6];
  const float* bk = (const float*)d_in[7];
  const float* Wv = (const float*)d_in[8];
  const float* bv = (const float*)d_in[9];
  const float* Wo = (const float*)d_in[10];
  const float* bo = (const float*)d_in[11];

  char* ws = (char*)d_ws;
  bf16_t* wtq = (bf16_t*)(ws + (0ull << 20));
  bf16_t* wtk = (bf16_t*)(ws + (2ull << 20));
  bf16_t* wtv = (bf16_t*)(ws + (4ull << 20));
  bf16_t* wto = (bf16_t*)(ws + (6ull << 20));
  bf16_t* qhb = (bf16_t*)(ws + (8ull << 20));
  bf16_t* khb = (bf16_t*)(ws + (24ull << 20));
  bf16_t* vtb = (bf16_t*)(ws + (40ull << 20));
  bf16_t* atb = (bf16_t*)(ws + (56ull << 20));

  dim3 tb(256);
  wt_kernel<<<dim3(32, 32), tb, 0, stream>>>(Wq, wtq);
  wt_kernel<<<dim3(32, 32), tb, 0, stream>>>(Wk, wtk);
  wt_kernel<<<dim3(32, 32), tb, 0, stream>>>(Wv, wtv);
  wt_kernel<<<dim3(32, 32), tb, 0, stream>>>(Wo, wto);

  dim3 gg(8, 64);  // N/128, M/128
  gemm_k<0><<<gg, tb, 0, stream>>>(q, wtq, bq, qhb);
  gemm_k<1><<<gg, tb, 0, stream>>>(k, wtk, bk, khb);
  gemm_k<2><<<gg, tb, 0, stream>>>(v, wtv, bv, vtb);

  attn_k<<<dim3(8, 64), dim3(512), 0, stream>>>(qhb, khb, vtb, atb);

  gemm_k<3><<<gg, tb, 0, stream>>>(atb, wto, bo, d_out);
}

// Round 4
// 195.210 us; speedup vs baseline: 3.1534x; 1.0268x over previous
//
#include <hip/hip_runtime.h>
#include <hip/hip_bf16.h>
#include <stdint.h>

#define B_ 4
#define S_ 2048
#define D_ 1024
#define H_ 16
#define HD_ 64

typedef __bf16 bf16_t;
typedef __bf16 bf16x8 __attribute__((ext_vector_type(8)));
typedef __bf16 bf16x2_t __attribute__((ext_vector_type(2)));
typedef float f32x4 __attribute__((ext_vector_type(4)));
typedef int i32x4 __attribute__((ext_vector_type(4)));

#define MFMA(a, b, c) __builtin_amdgcn_mfma_f32_16x16x32_bf16((a), (b), (c), 0, 0, 0)
#define LOG2E 1.44269504088896340736f

__device__ __forceinline__ void gload_lds16(const void* g, void* l) {
  __builtin_amdgcn_global_load_lds(
      (const __attribute__((address_space(1))) uint32_t*)g,
      (__attribute__((address_space(3))) uint32_t*)l, 16, 0, 0);
}

__device__ __forceinline__ float max3f(float a, float b, float c) {
  float d;
  asm("v_max3_f32 %0, %1, %2, %3" : "=v"(d) : "v"(a), "v"(b), "v"(c));
  return d;
}

// ---- weight transpose + convert: WT[n][k] = bf16(W[k][n]) -------------------
__global__ __launch_bounds__(256) void wt_kernel(const float* __restrict__ w,
                                                 bf16_t* __restrict__ wt) {
  __shared__ float t[32][33];
  const int tx = threadIdx.x & 31, ty = threadIdx.x >> 5;
  const int n0 = blockIdx.x * 32, k0 = blockIdx.y * 32;
#pragma unroll
  for (int i = 0; i < 4; i++)
    t[ty + i * 8][tx] = w[(size_t)(k0 + ty + i * 8) * D_ + n0 + tx];
  __syncthreads();
#pragma unroll
  for (int i = 0; i < 4; i++)
    wt[(size_t)(n0 + ty + i * 8) * D_ + k0 + tx] = (bf16_t)t[tx][ty + i * 8];
}

// ---- GEMM: C[8192x1024] = A[8192x1024] @ W + b ------------------------------
// MODE 0: A=f32 q,  out = bf16 Qh[(b*16+h)][s][hd] * 0.125
// MODE 1: A=f32 k,  out = bf16 Kh[(b*16+h)][s][hd]
// MODE 2: A=f32 v,  out = bf16 VT[(b*16+h)][hd][s]   (LDS-transposed epilogue)
// MODE 3: A=bf16 attn, out = f32 [m][n] + bias
template <int MODE>
__global__ __launch_bounds__(256) void gemm_k(const void* __restrict__ Av,
                                              const bf16_t* __restrict__ WT,
                                              const float* __restrict__ bias,
                                              void* __restrict__ Ov) {
  constexpr int K = D_;
  __shared__ bf16_t smem[17408];  // staging: A[128][64] + B[128][64]; MODE2 epi: [128][136]
  bf16_t* alds = smem;
  bf16_t* blds = smem + 8192;

  const int tid = threadIdx.x;
  const int w = tid >> 6, l = tid & 63;
  const int lr = l & 15, lg = l >> 4;
  const int wm = w >> 1, wn = w & 1;
  // XCD-chunked swizzle: 8 consecutive hw blocks (one per XCD) -> 8 m-panels;
  // each XCD sees 8 contiguous m-panels (4 MB A) reused across all 8 n-blocks.
  const int ib = (int)blockIdx.y * (int)gridDim.x + (int)blockIdx.x;  // 512 blocks
  const int swz = (ib & 7) * 64 + (ib >> 3);
  const int m0 = (swz >> 3) * 128, n0 = (swz & 7) * 128;

  f32x4 acc[4][4];
#pragma unroll
  for (int mt = 0; mt < 4; mt++)
#pragma unroll
    for (int nt = 0; nt < 4; nt++) {
      f32x4 z = {0.f, 0.f, 0.f, 0.f};
      acc[mt][nt] = z;
    }

  for (int k0 = 0; k0 < K; k0 += 64) {
    // stage B tile (WT rows = n), swizzled source -> linear LDS
#pragma unroll
    for (int c = 0; c < 4; c++) {
      int ci = c * 256 + w * 64 + l;
      int row = ci >> 3, kc = ci & 7;
      int ks = kc ^ (row & 7);
      gload_lds16(WT + (size_t)(n0 + row) * K + k0 + ks * 8,
                  blds + (size_t)(c * 256 + w * 64) * 8);
    }
    // stage A tile
    if constexpr (MODE != 3) {
      const float* A = (const float*)Av;
#pragma unroll
      for (int c = 0; c < 4; c++) {
        int ci = c * 256 + tid;
        int row = ci >> 3, kc = ci & 7;
        int ks = kc ^ (row & 7);
        const float* src = A + (size_t)(m0 + row) * K + k0 + ks * 8;
        float4 x0 = ((const float4*)src)[0];
        float4 x1 = ((const float4*)src)[1];
        bf16x8 vv;
        vv[0] = (bf16_t)x0.x; vv[1] = (bf16_t)x0.y; vv[2] = (bf16_t)x0.z; vv[3] = (bf16_t)x0.w;
        vv[4] = (bf16_t)x1.x; vv[5] = (bf16_t)x1.y; vv[6] = (bf16_t)x1.z; vv[7] = (bf16_t)x1.w;
        *reinterpret_cast<bf16x8*>(alds + (size_t)ci * 8) = vv;
      }
    } else {
      const bf16_t* A = (const bf16_t*)Av;
#pragma unroll
      for (int c = 0; c < 4; c++) {
        int ci = c * 256 + w * 64 + l;
        int row = ci >> 3, kc = ci & 7;
        int ks = kc ^ (row & 7);
        gload_lds16(A + (size_t)(m0 + row) * K + k0 + ks * 8,
                    alds + (size_t)(c * 256 + w * 64) * 8);
      }
    }
    __syncthreads();
#pragma unroll
    for (int kk = 0; kk < 2; kk++) {
      bf16x8 af[4], bfr[4];
#pragma unroll
      for (int mt = 0; mt < 4; mt++) {
        int row = wm * 64 + mt * 16 + lr;
        int kc = kk * 4 + lg;
        af[mt] = *reinterpret_cast<const bf16x8*>(alds + row * 64 + ((kc ^ (row & 7)) * 8));
      }
#pragma unroll
      for (int nt = 0; nt < 4; nt++) {
        int row = wn * 64 + nt * 16 + lr;
        int kc = kk * 4 + lg;
        bfr[nt] = *reinterpret_cast<const bf16x8*>(blds + row * 64 + ((kc ^ (row & 7)) * 8));
      }
#pragma unroll
      for (int mt = 0; mt < 4; mt++)
#pragma unroll
        for (int nt = 0; nt < 4; nt++)
          acc[mt][nt] = MFMA(af[mt], bfr[nt], acc[mt][nt]);
    }
    __syncthreads();
  }

  float bn[4];
#pragma unroll
  for (int nt = 0; nt < 4; nt++) bn[nt] = bias[n0 + wn * 64 + nt * 16 + lr];

  if constexpr (MODE == 0 || MODE == 1) {
    bf16_t* out = (bf16_t*)Ov;
#pragma unroll
    for (int mt = 0; mt < 4; mt++)
#pragma unroll
      for (int nt = 0; nt < 4; nt++)
#pragma unroll
        for (int r = 0; r < 4; r++) {
          int m = m0 + wm * 64 + mt * 16 + lg * 4 + r;
          int n = n0 + wn * 64 + nt * 16 + lr;
          float v = acc[mt][nt][r] + bn[nt];
          if constexpr (MODE == 0) v *= 0.125f;  // 1/sqrt(HD), exact in bf16
          int b = m >> 11, s = m & 2047, h = n >> 6, hd = n & 63;
          out[(((size_t)(b * H_ + h) * S_ + s) << 6) + hd] = (bf16_t)v;
        }
  } else if constexpr (MODE == 3) {
    float* out = (float*)Ov;
#pragma unroll
    for (int mt = 0; mt < 4; mt++)
#pragma unroll
      for (int nt = 0; nt < 4; nt++)
#pragma unroll
        for (int r = 0; r < 4; r++) {
          int m = m0 + wm * 64 + mt * 16 + lg * 4 + r;
          int n = n0 + wn * 64 + nt * 16 + lr;
          out[(size_t)m * D_ + n] = acc[mt][nt][r] + bn[nt];
        }
  } else {  // MODE 2: transpose in LDS, write VT[(b*16+h)][hd][s]
    __syncthreads();
#pragma unroll
    for (int mt = 0; mt < 4; mt++)
#pragma unroll
      for (int nt = 0; nt < 4; nt++)
#pragma unroll
        for (int r = 0; r < 4; r++) {
          int ml = wm * 64 + mt * 16 + lg * 4 + r;
          int nl = wn * 64 + nt * 16 + lr;
          smem[nl * 136 + ml] = (bf16_t)(acc[mt][nt][r] + bn[nt]);
        }
    __syncthreads();
    bf16_t* out = (bf16_t*)Ov;
    const int b = m0 >> 11, sbase = m0 & 2047;
#pragma unroll
    for (int c = 0; c < 8; c++) {
      int ci = c * 256 + tid;
      int dl = ci >> 4, sc = ci & 15;
      int n = n0 + dl, h = n >> 6, hd = n & 63;
      bf16x8 v = *reinterpret_cast<const bf16x8*>(smem + dl * 136 + sc * 8);
      *reinterpret_cast<bf16x8*>(out + ((size_t)((b * H_ + h) << 6) + hd) * S_ + sbase + sc * 8) = v;
    }
  }
}

// ---- causal flash attention ------------------------------------------------
// Qh,Kh [bh][s][hd], VT [bh][hd][s] -> attn [b][s][h*64+hd]
// 256 threads = 4 waves; QBLK=64 (wave w owns rows qt*64+w*16..+15).
// Block handles q-tile pair {p, 31-p}: uniform 34 kv-iters; 1024 blocks = 4/CU.
// Swapped QK^T (MFMA(K,Q)); K rows bit-permuted (pi) in LDS so P->PA is pure
// in-lane packs. li via ones-column MFMA. Raw v_exp_f32, v_max3, hoisted LDS
// addresses with pointer-swap double buffering. T13 defer-max; T5 setprio.
__global__ __launch_bounds__(256) void attn_k(const bf16_t* __restrict__ qh,
                                              const bf16_t* __restrict__ kh,
                                              const bf16_t* __restrict__ vt,
                                              bf16_t* __restrict__ attn) {
  __shared__ bf16_t kbuf[2][4096];
  __shared__ bf16_t vbuf[2][4096];

  const int tid = threadIdx.x, w = tid >> 6, l = tid & 63;
  const int lr = l & 15, lg = l >> 4;

  // XCD mapping: ib&7 = XCD; each XCD serves 8 bh (K/V 4MB = one L2)
  const int ib = (int)blockIdx.y * 16 + (int)blockIdx.x;  // [0,1024)
  const int xcd = ib & 7, slot = ib >> 3;
  const int bh = xcd * 8 + (slot & 7);
  const int pr = slot >> 3;  // pair index 0..15
  const int b = bh >> 4, h = bh & 15;

  // staging geometry: chunk i in {0,1}; slot-row zr_i = i*32 + tid>>3
  const int zr0 = tid >> 3, kc = tid & 7;
  const int sks = kc ^ (zr0 & 7);  // (32+zr0)&7 == zr0&7
  const int kprow0 = ((zr0 >> 5) & 1) * 32 + ((zr0 >> 2) & 3) * 8 + ((zr0 >> 4) & 1) * 4 + (zr0 & 3);
  const int zr1 = 32 + zr0;
  const int kprow1 = ((zr1 >> 5) & 1) * 32 + ((zr1 >> 2) & 3) * 8 + ((zr1 >> 4) & 1) * 4 + (zr1 & 3);
  const bf16_t* kbase0 = kh + ((size_t)bh * S_ + kprow0) * HD_ + sks * 8;
  const bf16_t* kbase1 = kh + ((size_t)bh * S_ + kprow1) * HD_ + sks * 8;
  const bf16_t* vbase0 = vt + ((size_t)bh * HD_ + zr0) * S_ + sks * 8;
  const bf16_t* vbase1 = vt + ((size_t)bh * HD_ + zr1) * S_ + sks * 8;

  // hoisted read offsets (swizzled, loop-invariant)
  const int xs7 = lr & 7;
  const int koffA = lr * 64 + ((lg ^ xs7) << 3);
  const int koffB = lr * 64 + (((lg ^ xs7) ^ 4) << 3);
  const int rowlim = w * 16 + lr;  // for diagonal-tile mask

  bf16x8 ones;
#pragma unroll
  for (int i = 0; i < 8; i++) ones[i] = (bf16_t)1.0f;

  for (int half = 0; half < 2; half++) {
    const int qt = half ? (31 - pr) : pr;
    const int q0 = qt * 64 + w * 16;

    const bf16_t* qp = qh + ((size_t)bh * S_ + q0 + lr) * HD_ + lg * 8;
    bf16x8 qf0 = *(const bf16x8*)qp;
    bf16x8 qf1 = *(const bf16x8*)(qp + 32);

    float mi = -1e30f;
    f32x4 o[4], os;
#pragma unroll
    for (int nt = 0; nt < 4; nt++) {
      f32x4 z = {0.f, 0.f, 0.f, 0.f};
      o[nt] = z;
    }
    {
      f32x4 z = {0.f, 0.f, 0.f, 0.f};
      os = z;
    }

    // per-half source pointers and double-buffer pointers
    const bf16_t *ks0 = kbase0, *ks1 = kbase1, *vs0 = vbase0, *vs1 = vbase1;
    const bf16_t *kcA = kbuf[0] + koffA, *kcB = kbuf[0] + koffB;
    const bf16_t *knA = kbuf[1] + koffA, *knB = kbuf[1] + koffB;
    const bf16_t *vcA = vbuf[0] + koffA, *vcB = vbuf[0] + koffB;
    const bf16_t *vnA = vbuf[1] + koffA, *vnB = vbuf[1] + koffB;
    bf16_t *kstC = kbuf[0] + w * 512, *kstN = kbuf[1] + w * 512;
    bf16_t *vstC = vbuf[0] + w * 512, *vstN = vbuf[1] + w * 512;

    // prologue: stage tile 0 into buf0
    gload_lds16(ks0, kstC);
    gload_lds16(ks1, kstC + 2048);
    gload_lds16(vs0, vstC);
    gload_lds16(vs1, vstC + 2048);
    ks0 += 64 * HD_; ks1 += 64 * HD_; vs0 += 64; vs1 += 64;
    __syncthreads();

    for (int jt = 0; jt <= qt; jt++) {
      if (jt < qt) {  // issue next-tile stage before compute
        gload_lds16(ks0, kstN);
        gload_lds16(ks1, kstN + 2048);
        gload_lds16(vs0, vstN);
        gload_lds16(vs1, vstN + 2048);
        ks0 += 64 * HD_; ks1 += 64 * HD_; vs0 += 64; vs1 += 64;
      }
      f32x4 s[4];
      __builtin_amdgcn_s_setprio(1);
#pragma unroll
      for (int nt = 0; nt < 4; nt++) {
        bf16x8 kf0 = *(const bf16x8*)(kcA + nt * 1024);
        bf16x8 kf1 = *(const bf16x8*)(kcB + nt * 1024);
        f32x4 a = {0.f, 0.f, 0.f, 0.f};
        a = MFMA(kf0, qf0, a);  // swapped: K as A-operand
        a = MFMA(kf1, qf1, a);
        s[nt] = a;
      }
      __builtin_amdgcn_s_setprio(0);
      // causal mask on the diagonal tile: kv = jt*64 + pi(nt,lg,r), row = q0+lr
      if (jt == qt) {
#pragma unroll
        for (int nt = 0; nt < 4; nt++) {
          int kvb = ((nt >> 1) << 5) + ((nt & 1) << 2) + lg * 8;
#pragma unroll
          for (int r = 0; r < 4; r++)
            if (kvb + r > rowlim) s[nt][r] = -1e30f;
        }
      }
      // row max: v_max3 tree + cross-copy reduce
      float m0 = max3f(s[0][0], s[0][1], s[0][2]);
      float m1 = max3f(s[0][3], s[1][0], s[1][1]);
      float m2 = max3f(s[1][2], s[1][3], s[2][0]);
      float m3 = max3f(s[2][1], s[2][2], s[2][3]);
      float m4 = max3f(s[3][0], s[3][1], s[3][2]);
      float mx = fmaxf(max3f(m0, m1, m2), max3f(m3, m4, s[3][3]));
      mx = fmaxf(mx, __shfl_xor(mx, 16));
      mx = fmaxf(mx, __shfl_xor(mx, 32));
      // T13 defer-max
      if (!__all(mx <= mi + 8.0f)) {
        float mn = fmaxf(mi, mx);
        float al = __builtin_amdgcn_exp2f((mi - mn) * LOG2E);
        mi = mn;
#pragma unroll
        for (int r = 0; r < 4; r++) {
          float alr = __shfl(al, lg * 4 + r);  // al of o's q-row (lg*4+r)
          o[0][r] *= alr; o[1][r] *= alr; o[2][r] *= alr; o[3][r] *= alr;
          os[r] *= alr;
        }
      }
      const float msc = mi * LOG2E;
#pragma unroll
      for (int nt = 0; nt < 4; nt++)
#pragma unroll
        for (int r = 0; r < 4; r++)
          s[nt][r] = __builtin_amdgcn_exp2f(s[nt][r] * LOG2E - msc);
      // P -> PA fragments: pure in-lane packs
      uint32_t pk[8];
#pragma unroll
      for (int nt = 0; nt < 4; nt++) {
        bf16x2_t plo = {(bf16_t)s[nt][0], (bf16_t)s[nt][1]};
        bf16x2_t phi = {(bf16_t)s[nt][2], (bf16_t)s[nt][3]};
        pk[nt * 2] = __builtin_bit_cast(uint32_t, plo);
        pk[nt * 2 + 1] = __builtin_bit_cast(uint32_t, phi);
      }
      i32x4 w0 = {(int)pk[0], (int)pk[1], (int)pk[2], (int)pk[3]};
      i32x4 w1 = {(int)pk[4], (int)pk[5], (int)pk[6], (int)pk[7]};
      bf16x8 pa0 = __builtin_bit_cast(bf16x8, w0);
      bf16x8 pa1 = __builtin_bit_cast(bf16x8, w1);
      __builtin_amdgcn_s_setprio(1);
#pragma unroll
      for (int ntd = 0; ntd < 4; ntd++) {
        bf16x8 vf0 = *(const bf16x8*)(vcA + ntd * 1024);
        bf16x8 vf1 = *(const bf16x8*)(vcB + ntd * 1024);
        o[ntd] = MFMA(pa0, vf0, o[ntd]);
        o[ntd] = MFMA(pa1, vf1, o[ntd]);
      }
      os = MFMA(pa0, ones, os);  // row-sum of P accumulates li in o-layout
      os = MFMA(pa1, ones, os);
      __builtin_amdgcn_s_setprio(0);
      __syncthreads();  // staged loads drained + buffer reads done
      // swap double-buffer pointers (phi nodes, no per-tile address math)
      { const bf16_t* t;
        t = kcA; kcA = knA; knA = t;  t = kcB; kcB = knB; knB = t;
        t = vcA; vcA = vnA; vnA = t;  t = vcB; vcB = vnB; vnB = t; }
      { bf16_t* t;
        t = kstC; kstC = kstN; kstN = t;  t = vstC; vstC = vstN; vstN = t; }
    }
    // epilogue: attn[b][s][h*64+hd]
#pragma unroll
    for (int r = 0; r < 4; r++) {
      float rinv = 1.f / os[r];
      int srw = q0 + lg * 4 + r;
#pragma unroll
      for (int ntd = 0; ntd < 4; ntd++)
        attn[((size_t)(b * S_ + srw)) * D_ + h * 64 + ntd * 16 + lr] =
            (bf16_t)(o[ntd][r] * rinv);
    }
    __syncthreads();  // buffers free before next half's prologue staging
  }
}

extern "C" void kernel_launch(void* const* d_in, const int* in_sizes, int n_in,
                              void* d_out, int out_size, void* d_ws, size_t ws_size,
                              hipStream_t stream) {
  (void)in_sizes; (void)n_in; (void)out_size; (void)ws_size;
  const float* q  = (const float*)d_in[0];
  const float* k  = (const float*)d_in[1];
  const float* v  = (const float*)d_in[2];
  // d_in[3] = mask: causal triu, hard-coded in attn_k
  const float* Wq = (const float*)d_in[4];
  const float* bq = (const float*)d_in[5];
  const float* Wk = (const float*)d_in[6];
  const float* bk = (const float*)d_in[7];
  const float* Wv = (const float*)d_in[8];
  const float* bv = (const float*)d_in[9];
  const float* Wo = (const float*)d_in[10];
  const float* bo = (const float*)d_in[11];

  char* ws = (char*)d_ws;
  bf16_t* wtq = (bf16_t*)(ws + (0ull << 20));
  bf16_t* wtk = (bf16_t*)(ws + (2ull << 20));
  bf16_t* wtv = (bf16_t*)(ws + (4ull << 20));
  bf16_t* wto = (bf16_t*)(ws + (6ull << 20));
  bf16_t* qhb = (bf16_t*)(ws + (8ull << 20));
  bf16_t* khb = (bf16_t*)(ws + (24ull << 20));
  bf16_t* vtb = (bf16_t*)(ws + (40ull << 20));
  bf16_t* atb = (bf16_t*)(ws + (56ull << 20));

  dim3 tb(256);
  wt_kernel<<<dim3(32, 32), tb, 0, stream>>>(Wq, wtq);
  wt_kernel<<<dim3(32, 32), tb, 0, stream>>>(Wk, wtk);
  wt_kernel<<<dim3(32, 32), tb, 0, stream>>>(Wv, wtv);
  wt_kernel<<<dim3(32, 32), tb, 0, stream>>>(Wo, wto);

  dim3 gg(8, 64);  // N/128, M/128
  gemm_k<0><<<gg, tb, 0, stream>>>(q, wtq, bq, qhb);
  gemm_k<1><<<gg, tb, 0, stream>>>(k, wtk, bk, khb);
  gemm_k<2><<<gg, tb, 0, stream>>>(v, wtv, bv, vtb);

  attn_k<<<dim3(16, 64), dim3(256), 0, stream>>>(qhb, khb, vtb, atb);

  gemm_k<3><<<gg, tb, 0, stream>>>(atb, wto, bo, d_out);
}

// Round 5
// 193.441 us; speedup vs baseline: 3.1822x; 1.0091x over previous
//
#include <hip/hip_runtime.h>
#include <hip/hip_bf16.h>
#include <stdint.h>

#define B_ 4
#define S_ 2048
#define D_ 1024
#define H_ 16
#define HD_ 64

typedef __bf16 bf16_t;
typedef __bf16 bf16x8 __attribute__((ext_vector_type(8)));
typedef __bf16 bf16x2_t __attribute__((ext_vector_type(2)));
typedef float f32x4 __attribute__((ext_vector_type(4)));
typedef int i32x4 __attribute__((ext_vector_type(4)));

#define MFMA(a, b, c) __builtin_amdgcn_mfma_f32_16x16x32_bf16((a), (b), (c), 0, 0, 0)
#define LOG2E 1.44269504088896340736f

__device__ __forceinline__ void gload_lds16(const void* g, void* l) {
  __builtin_amdgcn_global_load_lds(
      (const __attribute__((address_space(1))) uint32_t*)g,
      (__attribute__((address_space(3))) uint32_t*)l, 16, 0, 0);
}

__device__ __forceinline__ float max3f(float a, float b, float c) {
  float d;
  asm("v_max3_f32 %0, %1, %2, %3" : "=v"(d) : "v"(a), "v"(b), "v"(c));
  return d;
}

// ---- fused weight transpose + convert: WT[n][k] = bf16(W[k][n]), 4 weights --
__global__ __launch_bounds__(256) void wt_kernel(const float* __restrict__ Wq,
                                                 const float* __restrict__ Wk,
                                                 const float* __restrict__ Wv,
                                                 const float* __restrict__ Wo,
                                                 bf16_t* __restrict__ wt0) {
  __shared__ float t[32][33];
  const int z = blockIdx.z;
  const float* w_ = z == 0 ? Wq : (z == 1 ? Wk : (z == 2 ? Wv : Wo));
  bf16_t* wt = wt0 + (size_t)z * (1u << 20);
  const int tx = threadIdx.x & 31, ty = threadIdx.x >> 5;
  const int n0 = blockIdx.x * 32, k0 = blockIdx.y * 32;
#pragma unroll
  for (int i = 0; i < 4; i++)
    t[ty + i * 8][tx] = w_[(size_t)(k0 + ty + i * 8) * D_ + n0 + tx];
  __syncthreads();
#pragma unroll
  for (int i = 0; i < 4; i++)
    wt[(size_t)(n0 + ty + i * 8) * D_ + k0 + tx] = (bf16_t)t[tx][ty + i * 8];
}

// ---- fused QKV projection GEMM: one dispatch, z = 0(Q)/1(K)/2(V) -----------
// z 0: out = bf16 Qh[(b*16+h)][s][hd] * 0.125
// z 1: out = bf16 Kh[(b*16+h)][s][hd]
// z 2: out = bf16 VT[(b*16+h)][hd][s]   (LDS-transposed epilogue)
__global__ __launch_bounds__(256) void qkv_gemm(const float* __restrict__ qi,
                                                const float* __restrict__ ki,
                                                const float* __restrict__ vi,
                                                const bf16_t* __restrict__ wt0,
                                                const float* __restrict__ bq,
                                                const float* __restrict__ bk,
                                                const float* __restrict__ bv,
                                                bf16_t* __restrict__ out0) {
  constexpr int K = D_;
  __shared__ bf16_t smem[17408];
  bf16_t* alds = smem;
  bf16_t* blds = smem + 8192;

  const int z = blockIdx.z;
  const float* A = z == 0 ? qi : (z == 1 ? ki : vi);
  const bf16_t* WT = wt0 + (size_t)z * (1u << 20);
  const float* bias = z == 0 ? bq : (z == 1 ? bk : bv);
  bf16_t* out = out0 + (size_t)z * (8u << 20);

  const int tid = threadIdx.x;
  const int w = tid >> 6, l = tid & 63;
  const int lr = l & 15, lg = l >> 4;
  const int wm = w >> 1, wn = w & 1;
  // XCD-chunked swizzle within each z-slice (512 blocks; 512%8==0 keeps it aligned)
  const int ib = (int)blockIdx.y * (int)gridDim.x + (int)blockIdx.x;
  const int swz = (ib & 7) * 64 + (ib >> 3);
  const int m0 = (swz >> 3) * 128, n0 = (swz & 7) * 128;

  f32x4 acc[4][4];
#pragma unroll
  for (int mt = 0; mt < 4; mt++)
#pragma unroll
    for (int nt = 0; nt < 4; nt++) {
      f32x4 zz = {0.f, 0.f, 0.f, 0.f};
      acc[mt][nt] = zz;
    }

  for (int k0 = 0; k0 < K; k0 += 64) {
#pragma unroll
    for (int c = 0; c < 4; c++) {
      int ci = c * 256 + w * 64 + l;
      int row = ci >> 3, kc = ci & 7;
      int ks = kc ^ (row & 7);
      gload_lds16(WT + (size_t)(n0 + row) * K + k0 + ks * 8,
                  blds + (size_t)(c * 256 + w * 64) * 8);
    }
#pragma unroll
    for (int c = 0; c < 4; c++) {
      int ci = c * 256 + tid;
      int row = ci >> 3, kc = ci & 7;
      int ks = kc ^ (row & 7);
      const float* src = A + (size_t)(m0 + row) * K + k0 + ks * 8;
      float4 x0 = ((const float4*)src)[0];
      float4 x1 = ((const float4*)src)[1];
      bf16x8 vv;
      vv[0] = (bf16_t)x0.x; vv[1] = (bf16_t)x0.y; vv[2] = (bf16_t)x0.z; vv[3] = (bf16_t)x0.w;
      vv[4] = (bf16_t)x1.x; vv[5] = (bf16_t)x1.y; vv[6] = (bf16_t)x1.z; vv[7] = (bf16_t)x1.w;
      *reinterpret_cast<bf16x8*>(alds + (size_t)ci * 8) = vv;
    }
    __syncthreads();
#pragma unroll
    for (int kk = 0; kk < 2; kk++) {
      bf16x8 af[4], bfr[4];
#pragma unroll
      for (int mt = 0; mt < 4; mt++) {
        int row = wm * 64 + mt * 16 + lr;
        int kc = kk * 4 + lg;
        af[mt] = *reinterpret_cast<const bf16x8*>(alds + row * 64 + ((kc ^ (row & 7)) * 8));
      }
#pragma unroll
      for (int nt = 0; nt < 4; nt++) {
        int row = wn * 64 + nt * 16 + lr;
        int kc = kk * 4 + lg;
        bfr[nt] = *reinterpret_cast<const bf16x8*>(blds + row * 64 + ((kc ^ (row & 7)) * 8));
      }
#pragma unroll
      for (int mt = 0; mt < 4; mt++)
#pragma unroll
        for (int nt = 0; nt < 4; nt++)
          acc[mt][nt] = MFMA(af[mt], bfr[nt], acc[mt][nt]);
    }
    __syncthreads();
  }

  float bn[4];
#pragma unroll
  for (int nt = 0; nt < 4; nt++) bn[nt] = bias[n0 + wn * 64 + nt * 16 + lr];

  if (z != 2) {
    const float sc = z == 0 ? 0.125f : 1.0f;  // 1/sqrt(HD) exact in bf16
#pragma unroll
    for (int mt = 0; mt < 4; mt++)
#pragma unroll
      for (int nt = 0; nt < 4; nt++)
#pragma unroll
        for (int r = 0; r < 4; r++) {
          int m = m0 + wm * 64 + mt * 16 + lg * 4 + r;
          int n = n0 + wn * 64 + nt * 16 + lr;
          float v = (acc[mt][nt][r] + bn[nt]) * sc;
          int b = m >> 11, s = m & 2047, h = n >> 6, hd = n & 63;
          out[(((size_t)(b * H_ + h) * S_ + s) << 6) + hd] = (bf16_t)v;
        }
  } else {  // V: transpose in LDS, write VT[(b*16+h)][hd][s]
    __syncthreads();
#pragma unroll
    for (int mt = 0; mt < 4; mt++)
#pragma unroll
      for (int nt = 0; nt < 4; nt++)
#pragma unroll
        for (int r = 0; r < 4; r++) {
          int ml = wm * 64 + mt * 16 + lg * 4 + r;
          int nl = wn * 64 + nt * 16 + lr;
          smem[nl * 136 + ml] = (bf16_t)(acc[mt][nt][r] + bn[nt]);
        }
    __syncthreads();
    const int b = m0 >> 11, sbase = m0 & 2047;
#pragma unroll
    for (int c = 0; c < 8; c++) {
      int ci = c * 256 + tid;
      int dl = ci >> 4, sc2 = ci & 15;
      int n = n0 + dl, h = n >> 6, hd = n & 63;
      bf16x8 v = *reinterpret_cast<const bf16x8*>(smem + dl * 136 + sc2 * 8);
      *reinterpret_cast<bf16x8*>(out + ((size_t)((b * H_ + h) << 6) + hd) * S_ + sbase + sc2 * 8) = v;
    }
  }
}

// ---- output GEMM: C[8192x1024] = attn(bf16) @ WoT + bo, f32 out ------------
__global__ __launch_bounds__(256) void out_gemm(const bf16_t* __restrict__ A,
                                                const bf16_t* __restrict__ WT,
                                                const float* __restrict__ bias,
                                                float* __restrict__ out) {
  constexpr int K = D_;
  __shared__ bf16_t smem[16384];
  bf16_t* alds = smem;
  bf16_t* blds = smem + 8192;

  const int tid = threadIdx.x;
  const int w = tid >> 6, l = tid & 63;
  const int lr = l & 15, lg = l >> 4;
  const int wm = w >> 1, wn = w & 1;
  const int ib = (int)blockIdx.y * (int)gridDim.x + (int)blockIdx.x;
  const int swz = (ib & 7) * 64 + (ib >> 3);
  const int m0 = (swz >> 3) * 128, n0 = (swz & 7) * 128;

  f32x4 acc[4][4];
#pragma unroll
  for (int mt = 0; mt < 4; mt++)
#pragma unroll
    for (int nt = 0; nt < 4; nt++) {
      f32x4 z = {0.f, 0.f, 0.f, 0.f};
      acc[mt][nt] = z;
    }

  for (int k0 = 0; k0 < K; k0 += 64) {
#pragma unroll
    for (int c = 0; c < 4; c++) {
      int ci = c * 256 + w * 64 + l;
      int row = ci >> 3, kc = ci & 7;
      int ks = kc ^ (row & 7);
      gload_lds16(WT + (size_t)(n0 + row) * K + k0 + ks * 8,
                  blds + (size_t)(c * 256 + w * 64) * 8);
      gload_lds16(A + (size_t)(m0 + row) * K + k0 + ks * 8,
                  alds + (size_t)(c * 256 + w * 64) * 8);
    }
    __syncthreads();
#pragma unroll
    for (int kk = 0; kk < 2; kk++) {
      bf16x8 af[4], bfr[4];
#pragma unroll
      for (int mt = 0; mt < 4; mt++) {
        int row = wm * 64 + mt * 16 + lr;
        int kc = kk * 4 + lg;
        af[mt] = *reinterpret_cast<const bf16x8*>(alds + row * 64 + ((kc ^ (row & 7)) * 8));
      }
#pragma unroll
      for (int nt = 0; nt < 4; nt++) {
        int row = wn * 64 + nt * 16 + lr;
        int kc = kk * 4 + lg;
        bfr[nt] = *reinterpret_cast<const bf16x8*>(blds + row * 64 + ((kc ^ (row & 7)) * 8));
      }
#pragma unroll
      for (int mt = 0; mt < 4; mt++)
#pragma unroll
        for (int nt = 0; nt < 4; nt++)
          acc[mt][nt] = MFMA(af[mt], bfr[nt], acc[mt][nt]);
    }
    __syncthreads();
  }

  float bn[4];
#pragma unroll
  for (int nt = 0; nt < 4; nt++) bn[nt] = bias[n0 + wn * 64 + nt * 16 + lr];
#pragma unroll
  for (int mt = 0; mt < 4; mt++)
#pragma unroll
    for (int nt = 0; nt < 4; nt++)
#pragma unroll
      for (int r = 0; r < 4; r++) {
        int m = m0 + wm * 64 + mt * 16 + lg * 4 + r;
        int n = n0 + wn * 64 + nt * 16 + lr;
        out[(size_t)m * D_ + n] = acc[mt][nt][r] + bn[nt];
      }
}

// ---- causal flash attention ------------------------------------------------
// 256 threads = 4 waves; QBLK=64; block handles q-tile pair {p, 31-p}.
// 3-buffer LDS ring, 2 tiles prefetched ahead, counted vmcnt(8) + raw
// s_barrier (T3/T4): staging loads span iterations, never drained to 0.
__global__ __launch_bounds__(256) void attn_k(const bf16_t* __restrict__ qh,
                                              const bf16_t* __restrict__ kh,
                                              const bf16_t* __restrict__ vt,
                                              bf16_t* __restrict__ attn) {
  __shared__ bf16_t kbuf[3][4096];
  __shared__ bf16_t vbuf[3][4096];

  const int tid = threadIdx.x, w = tid >> 6, l = tid & 63;
  const int lr = l & 15, lg = l >> 4;

  // XCD mapping: ib&7 = XCD; each XCD serves 8 bh
  const int ib = (int)blockIdx.y * 16 + (int)blockIdx.x;  // [0,1024)
  const int xcd = ib & 7, slot = ib >> 3;
  const int bh = xcd * 8 + (slot & 7);
  const int pr = slot >> 3;  // pair index 0..15
  const int b = bh >> 4, h = bh & 15;

  // staging geometry: chunk i in {0,1}; slot-row zr_i = i*32 + tid>>3
  const int zr0 = tid >> 3, kc = tid & 7;
  const int sks = kc ^ (zr0 & 7);
  const int kprow0 = ((zr0 >> 5) & 1) * 32 + ((zr0 >> 2) & 3) * 8 + ((zr0 >> 4) & 1) * 4 + (zr0 & 3);
  const int zr1 = 32 + zr0;
  const int kprow1 = ((zr1 >> 5) & 1) * 32 + ((zr1 >> 2) & 3) * 8 + ((zr1 >> 4) & 1) * 4 + (zr1 & 3);
  const bf16_t* kbase0 = kh + ((size_t)bh * S_ + kprow0) * HD_ + sks * 8;
  const bf16_t* kbase1 = kh + ((size_t)bh * S_ + kprow1) * HD_ + sks * 8;
  const bf16_t* vbase0 = vt + ((size_t)bh * HD_ + zr0) * S_ + sks * 8;
  const bf16_t* vbase1 = vt + ((size_t)bh * HD_ + zr1) * S_ + sks * 8;

  const int xs7 = lr & 7;
  const int koffA = lr * 64 + ((lg ^ xs7) << 3);
  const int koffB = lr * 64 + (((lg ^ xs7) ^ 4) << 3);
  const int rowlim = w * 16 + lr;
  const int wsl = w * 512;  // wave staging slice

  bf16x8 ones;
#pragma unroll
  for (int i = 0; i < 8; i++) ones[i] = (bf16_t)1.0f;

  for (int half = 0; half < 2; half++) {
    const int qt = half ? (31 - pr) : pr;
    const int q0 = qt * 64 + w * 16;

    const bf16_t* qp = qh + ((size_t)bh * S_ + q0 + lr) * HD_ + lg * 8;
    bf16x8 qf0 = *(const bf16x8*)qp;
    bf16x8 qf1 = *(const bf16x8*)(qp + 32);

    float mi = -1e30f;
    f32x4 o[4], os;
#pragma unroll
    for (int nt = 0; nt < 4; nt++) {
      f32x4 z = {0.f, 0.f, 0.f, 0.f};
      o[nt] = z;
    }
    {
      f32x4 z = {0.f, 0.f, 0.f, 0.f};
      os = z;
    }

    const bf16_t *ks0 = kbase0, *ks1 = kbase1, *vs0 = vbase0, *vs1 = vbase1;
    int jsrc = 0;

    // issue one tile's staging (4 loads); clamp advance at tile qt (dead
    // re-stages keep the vmcnt accounting uniform and stay in-bounds)
#define ISSUE_STAGE(bi)                                        \
    do {                                                       \
      gload_lds16(ks0, &kbuf[bi][wsl]);                        \
      gload_lds16(ks1, &kbuf[bi][wsl + 2048]);                 \
      gload_lds16(vs0, &vbuf[bi][wsl]);                        \
      gload_lds16(vs1, &vbuf[bi][wsl + 2048]);                 \
      if (jsrc < qt) {                                         \
        ks0 += 64 * HD_; ks1 += 64 * HD_; vs0 += 64; vs1 += 64; \
        jsrc++;                                                \
      }                                                        \
    } while (0)

    // prologue: stage tiles 0 and 1
    ISSUE_STAGE(0);
    ISSUE_STAGE(1);
    asm volatile("s_waitcnt vmcnt(4)" ::: "memory");  // stage(0) landed
    __builtin_amdgcn_s_barrier();
    __builtin_amdgcn_sched_barrier(0);

    int cidx = 0, c2 = 2;
    for (int jt = 0; jt <= qt; jt++) {
      ISSUE_STAGE(c2);                                  // stage(jt+2)
      asm volatile("s_waitcnt vmcnt(8)" ::: "memory");  // own stage(jt) landed
      __builtin_amdgcn_s_barrier();                     // everyone's landed
      __builtin_amdgcn_sched_barrier(0);

      const bf16_t* kt = kbuf[cidx];
      const bf16_t* vb = vbuf[cidx];
      f32x4 s[4];
      __builtin_amdgcn_s_setprio(1);
#pragma unroll
      for (int nt = 0; nt < 4; nt++) {
        bf16x8 kf0 = *(const bf16x8*)(kt + koffA + nt * 1024);
        bf16x8 kf1 = *(const bf16x8*)(kt + koffB + nt * 1024);
        f32x4 a = {0.f, 0.f, 0.f, 0.f};
        a = MFMA(kf0, qf0, a);  // swapped: K as A-operand
        a = MFMA(kf1, qf1, a);
        s[nt] = a;
      }
      __builtin_amdgcn_s_setprio(0);
      if (jt == qt) {  // diagonal tile: causal mask, kv = pi(nt,lg,r)
#pragma unroll
        for (int nt = 0; nt < 4; nt++) {
          int kvb = ((nt >> 1) << 5) + ((nt & 1) << 2) + lg * 8;
#pragma unroll
          for (int r = 0; r < 4; r++)
            if (kvb + r > rowlim) s[nt][r] = -1e30f;
        }
      }
      // row max: v_max3 tree + cross-copy reduce
      float m0 = max3f(s[0][0], s[0][1], s[0][2]);
      float m1 = max3f(s[0][3], s[1][0], s[1][1]);
      float m2 = max3f(s[1][2], s[1][3], s[2][0]);
      float m3 = max3f(s[2][1], s[2][2], s[2][3]);
      float m4 = max3f(s[3][0], s[3][1], s[3][2]);
      float mx = fmaxf(max3f(m0, m1, m2), max3f(m3, m4, s[3][3]));
      mx = fmaxf(mx, __shfl_xor(mx, 16));
      mx = fmaxf(mx, __shfl_xor(mx, 32));
      // T13 defer-max
      if (!__all(mx <= mi + 8.0f)) {
        float mn = fmaxf(mi, mx);
        float al = __builtin_amdgcn_exp2f((mi - mn) * LOG2E);
        mi = mn;
#pragma unroll
        for (int r = 0; r < 4; r++) {
          float alr = __shfl(al, lg * 4 + r);
          o[0][r] *= alr; o[1][r] *= alr; o[2][r] *= alr; o[3][r] *= alr;
          os[r] *= alr;
        }
      }
      const float msc = mi * LOG2E;
#pragma unroll
      for (int nt = 0; nt < 4; nt++)
#pragma unroll
        for (int r = 0; r < 4; r++)
          s[nt][r] = __builtin_amdgcn_exp2f(s[nt][r] * LOG2E - msc);
      // P -> PA fragments: pure in-lane packs
      uint32_t pk[8];
#pragma unroll
      for (int nt = 0; nt < 4; nt++) {
        bf16x2_t plo = {(bf16_t)s[nt][0], (bf16_t)s[nt][1]};
        bf16x2_t phi = {(bf16_t)s[nt][2], (bf16_t)s[nt][3]};
        pk[nt * 2] = __builtin_bit_cast(uint32_t, plo);
        pk[nt * 2 + 1] = __builtin_bit_cast(uint32_t, phi);
      }
      i32x4 w0 = {(int)pk[0], (int)pk[1], (int)pk[2], (int)pk[3]};
      i32x4 w1 = {(int)pk[4], (int)pk[5], (int)pk[6], (int)pk[7]};
      bf16x8 pa0 = __builtin_bit_cast(bf16x8, w0);
      bf16x8 pa1 = __builtin_bit_cast(bf16x8, w1);
      __builtin_amdgcn_s_setprio(1);
#pragma unroll
      for (int ntd = 0; ntd < 4; ntd++) {
        bf16x8 vf0 = *(const bf16x8*)(vb + koffA + ntd * 1024);
        bf16x8 vf1 = *(const bf16x8*)(vb + koffB + ntd * 1024);
        o[ntd] = MFMA(pa0, vf0, o[ntd]);
        o[ntd] = MFMA(pa1, vf1, o[ntd]);
      }
      os = MFMA(pa0, ones, os);
      os = MFMA(pa1, ones, os);
      __builtin_amdgcn_s_setprio(0);

      __builtin_amdgcn_sched_barrier(0);
      __builtin_amdgcn_s_barrier();  // WAR: reads done before buf reuse
      __builtin_amdgcn_sched_barrier(0);
      cidx = (cidx == 2) ? 0 : cidx + 1;
      c2 = (c2 == 2) ? 0 : c2 + 1;
    }
#undef ISSUE_STAGE
    // epilogue: attn[b][s][h*64+hd]
#pragma unroll
    for (int r = 0; r < 4; r++) {
      float rinv = 1.f / os[r];
      int srw = q0 + lg * 4 + r;
#pragma unroll
      for (int ntd = 0; ntd < 4; ntd++)
        attn[((size_t)(b * S_ + srw)) * D_ + h * 64 + ntd * 16 + lr] =
            (bf16_t)(o[ntd][r] * rinv);
    }
  }
}

extern "C" void kernel_launch(void* const* d_in, const int* in_sizes, int n_in,
                              void* d_out, int out_size, void* d_ws, size_t ws_size,
                              hipStream_t stream) {
  (void)in_sizes; (void)n_in; (void)out_size; (void)ws_size;
  const float* q  = (const float*)d_in[0];
  const float* k  = (const float*)d_in[1];
  const float* v  = (const float*)d_in[2];
  // d_in[3] = mask: causal triu, hard-coded in attn_k
  const float* Wq = (const float*)d_in[4];
  const float* bq = (const float*)d_in[5];
  const float* Wk = (const float*)d_in[6];
  const float* bk = (const float*)d_in[7];
  const float* Wv = (const float*)d_in[8];
  const float* bv = (const float*)d_in[9];
  const float* Wo = (const float*)d_in[10];
  const float* bo = (const float*)d_in[11];

  char* ws = (char*)d_ws;
  bf16_t* wt0 = (bf16_t*)(ws + (0ull << 20));   // wtq/wtk/wtv/wto, 2MB apart
  bf16_t* wto = (bf16_t*)(ws + (6ull << 20));
  bf16_t* qhb = (bf16_t*)(ws + (8ull << 20));   // qhb/khb/vtb, 16MB apart
  bf16_t* khb = (bf16_t*)(ws + (24ull << 20));
  bf16_t* vtb = (bf16_t*)(ws + (40ull << 20));
  bf16_t* atb = (bf16_t*)(ws + (56ull << 20));

  dim3 tb(256);
  wt_kernel<<<dim3(32, 32, 4), tb, 0, stream>>>(Wq, Wk, Wv, Wo, wt0);
  qkv_gemm<<<dim3(8, 64, 3), tb, 0, stream>>>(q, k, v, wt0, bq, bk, bv, qhb);
  attn_k<<<dim3(16, 64), tb, 0, stream>>>(qhb, khb, vtb, atb);
  out_gemm<<<dim3(8, 64), tb, 0, stream>>>(atb, wto, bo, (float*)d_out);
}

// Round 6
// 186.671 us; speedup vs baseline: 3.2976x; 1.0363x over previous
//
#include <hip/hip_runtime.h>
#include <hip/hip_bf16.h>
#include <stdint.h>

#define B_ 4
#define S_ 2048
#define D_ 1024
#define H_ 16
#define HD_ 64

typedef __bf16 bf16_t;
typedef __bf16 bf16x8 __attribute__((ext_vector_type(8)));
typedef __bf16 bf16x2_t __attribute__((ext_vector_type(2)));
typedef float f32x4 __attribute__((ext_vector_type(4)));
typedef int i32x4 __attribute__((ext_vector_type(4)));

#define MFMA(a, b, c) __builtin_amdgcn_mfma_f32_16x16x32_bf16((a), (b), (c), 0, 0, 0)
#define LOG2E 1.44269504088896340736f

__device__ __forceinline__ void gload_lds16(const void* g, void* l) {
  __builtin_amdgcn_global_load_lds(
      (const __attribute__((address_space(1))) uint32_t*)g,
      (__attribute__((address_space(3))) uint32_t*)l, 16, 0, 0);
}

__device__ __forceinline__ float max3f(float a, float b, float c) {
  float d;
  asm("v_max3_f32 %0, %1, %2, %3" : "=v"(d) : "v"(a), "v"(b), "v"(c));
  return d;
}

// ---- fused weight transpose + convert: WT[n][k] = bf16(W[k][n]), 4 weights --
__global__ __launch_bounds__(256) void wt_kernel(const float* __restrict__ Wq,
                                                 const float* __restrict__ Wk,
                                                 const float* __restrict__ Wv,
                                                 const float* __restrict__ Wo,
                                                 bf16_t* __restrict__ wt0) {
  __shared__ float t[32][33];
  const int z = blockIdx.z;
  const float* w_ = z == 0 ? Wq : (z == 1 ? Wk : (z == 2 ? Wv : Wo));
  bf16_t* wt = wt0 + (size_t)z * (1u << 20);
  const int tx = threadIdx.x & 31, ty = threadIdx.x >> 5;
  const int n0 = blockIdx.x * 32, k0 = blockIdx.y * 32;
#pragma unroll
  for (int i = 0; i < 4; i++)
    t[ty + i * 8][tx] = w_[(size_t)(k0 + ty + i * 8) * D_ + n0 + tx];
  __syncthreads();
#pragma unroll
  for (int i = 0; i < 4; i++)
    wt[(size_t)(n0 + ty + i * 8) * D_ + k0 + tx] = (bf16_t)t[tx][ty + i * 8];
}

// ---- q/k/v f32 -> bf16 (flat, same layout): one dispatch, z picks source ---
__global__ __launch_bounds__(256) void conv_kernel(const float* __restrict__ q,
                                                   const float* __restrict__ k,
                                                   const float* __restrict__ v,
                                                   bf16_t* __restrict__ out) {
  const int z = blockIdx.z;
  const float* src = z == 0 ? q : (z == 1 ? k : v);
  bf16_t* dst = out + (size_t)z * 8388608u;
  const size_t i = ((size_t)blockIdx.x * 256 + threadIdx.x) * 8;
  float4 x0 = *(const float4*)(src + i);
  float4 x1 = *(const float4*)(src + i + 4);
  bf16x8 vv;
  vv[0] = (bf16_t)x0.x; vv[1] = (bf16_t)x0.y; vv[2] = (bf16_t)x0.z; vv[3] = (bf16_t)x0.w;
  vv[4] = (bf16_t)x1.x; vv[5] = (bf16_t)x1.y; vv[6] = (bf16_t)x1.z; vv[7] = (bf16_t)x1.w;
  *(bf16x8*)(dst + i) = vv;
}

// ---- ring GEMM: C[8192x1024] = A(bf16) @ WT^T + b ---------------------------
// 2-buffer LDS ring, tile j+2 staged after the WAR barrier, counted vmcnt(8)
// (stage j+1 stays in flight across barriers; stage j guaranteed landed).
// QKV=true: grid.z = 0(Q)/1(K)/2(V), bf16 head-split outputs (V transposed).
// QKV=false: single slice, f32 [m][n] + bias (final projection).
template <bool QKV>
__global__ __launch_bounds__(256) void mm_kernel(const bf16_t* __restrict__ A0,
                                                 const bf16_t* __restrict__ wt0,
                                                 const float* __restrict__ b0,
                                                 const float* __restrict__ b1,
                                                 const float* __restrict__ b2,
                                                 void* __restrict__ out0) {
  __shared__ bf16_t smem[32768];  // 2 bufs x (A[128][64] + B[128][64])

  const int z = QKV ? blockIdx.z : 0;
  const bf16_t* A = A0 + (size_t)z * 8388608u;
  const bf16_t* WT = wt0 + (size_t)z * 1048576u;
  const float* bias = QKV ? (z == 0 ? b0 : (z == 1 ? b1 : b2)) : b0;

  const int tid = threadIdx.x;
  const int w = tid >> 6, l = tid & 63;
  const int lr = l & 15, lg = l >> 4;
  const int wm = w >> 1, wn = w & 1;
  // XCD-chunked swizzle: 8 consecutive hw blocks -> 8 m-panels on one XCD
  const int ib = (int)blockIdx.y * 8 + (int)blockIdx.x;  // 512 blocks/slice
  const int swz = (ib & 7) * 64 + (ib >> 3);
  const int m0 = (swz >> 3) * 128, n0 = (swz & 7) * 128;

  // hoisted staging addresses: chunk c covers rows c*32 + (tid>>3)
  const int row0 = tid >> 3;
  const int ks = (tid & 7) ^ (row0 & 7);  // (c*32+row0)&7 == row0&7
  const bf16_t* aS = A + (size_t)(m0 + row0) * 1024 + ks * 8;
  const bf16_t* bS = WT + (size_t)(n0 + row0) * 1024 + ks * 8;
  const int wsl = w * 512;  // wave-uniform LDS chunk base (elements)

  f32x4 acc[4][4];
#pragma unroll
  for (int mt = 0; mt < 4; mt++)
#pragma unroll
    for (int nt = 0; nt < 4; nt++) {
      f32x4 zz = {0.f, 0.f, 0.f, 0.f};
      acc[mt][nt] = zz;
    }

// stage tile (kt = tile*64) into buffer bi: 8 gload_lds per thread
#define STAGE(bi, kt)                                                   \
  do {                                                                  \
    bf16_t* ad = smem + (bi) * 16384 + wsl;                             \
    bf16_t* bd = smem + (bi) * 16384 + 8192 + wsl;                      \
    _Pragma("unroll") for (int c = 0; c < 4; c++) {                     \
      gload_lds16(bS + (size_t)c * 32768 + (kt), bd + c * 2048);        \
      gload_lds16(aS + (size_t)c * 32768 + (kt), ad + c * 2048);        \
    }                                                                   \
  } while (0)

  // prologue: tiles 0 and 1
  STAGE(0, 0);
  STAGE(1, 64);
  asm volatile("s_waitcnt vmcnt(8)" ::: "memory");  // stage(0) landed
  __builtin_amdgcn_s_barrier();
  __builtin_amdgcn_sched_barrier(0);

  int buf = 0;
  for (int jt = 0; jt < 16; ++jt) {
    const bf16_t* alds = smem + buf * 16384;
    const bf16_t* blds = alds + 8192;
#pragma unroll
    for (int kk = 0; kk < 2; kk++) {
      bf16x8 af[4], bfr[4];
#pragma unroll
      for (int mt = 0; mt < 4; mt++) {
        int row = wm * 64 + mt * 16 + lr;
        int kc = kk * 4 + lg;
        af[mt] = *reinterpret_cast<const bf16x8*>(alds + row * 64 + ((kc ^ (row & 7)) * 8));
      }
#pragma unroll
      for (int nt = 0; nt < 4; nt++) {
        int row = wn * 64 + nt * 16 + lr;
        int kc = kk * 4 + lg;
        bfr[nt] = *reinterpret_cast<const bf16x8*>(blds + row * 64 + ((kc ^ (row & 7)) * 8));
      }
#pragma unroll
      for (int mt = 0; mt < 4; mt++)
#pragma unroll
        for (int nt = 0; nt < 4; nt++)
          acc[mt][nt] = MFMA(af[mt], bfr[nt], acc[mt][nt]);
    }
    if (jt == 15) break;
    __builtin_amdgcn_sched_barrier(0);
    __builtin_amdgcn_s_barrier();  // WAR: all readers done with buf
    __builtin_amdgcn_sched_barrier(0);
    const int tn = (jt + 2 < 16) ? jt + 2 : 15;  // dead re-stage keeps count uniform
    STAGE(buf, tn * 64);
    asm volatile("s_waitcnt vmcnt(8)" ::: "memory");  // stage(jt+1) landed
    __builtin_amdgcn_s_barrier();                     // RAW
    __builtin_amdgcn_sched_barrier(0);
    buf ^= 1;
  }
#undef STAGE

  float bn[4];
#pragma unroll
  for (int nt = 0; nt < 4; nt++) bn[nt] = bias[n0 + wn * 64 + nt * 16 + lr];

  if (!QKV) {
    float* out = (float*)out0;
#pragma unroll
    for (int mt = 0; mt < 4; mt++)
#pragma unroll
      for (int nt = 0; nt < 4; nt++)
#pragma unroll
        for (int r = 0; r < 4; r++) {
          int m = m0 + wm * 64 + mt * 16 + lg * 4 + r;
          int n = n0 + wn * 64 + nt * 16 + lr;
          out[(size_t)m * D_ + n] = acc[mt][nt][r] + bn[nt];
        }
  } else if (z != 2) {
    bf16_t* out = (bf16_t*)out0 + (size_t)z * 8388608u;
    const float sc = z == 0 ? 0.125f : 1.0f;  // 1/sqrt(HD) exact in bf16
#pragma unroll
    for (int mt = 0; mt < 4; mt++)
#pragma unroll
      for (int nt = 0; nt < 4; nt++)
#pragma unroll
        for (int r = 0; r < 4; r++) {
          int m = m0 + wm * 64 + mt * 16 + lg * 4 + r;
          int n = n0 + wn * 64 + nt * 16 + lr;
          float v = (acc[mt][nt][r] + bn[nt]) * sc;
          int b = m >> 11, s = m & 2047, h = n >> 6, hd = n & 63;
          out[(((size_t)(b * H_ + h) * S_ + s) << 6) + hd] = (bf16_t)v;
        }
  } else {  // V: transpose in LDS, write VT[(b*16+h)][hd][s]
    bf16_t* out = (bf16_t*)out0 + (size_t)z * 8388608u;
    __syncthreads();  // drains vmcnt (incl. dead re-stage) + all waves done
#pragma unroll
    for (int mt = 0; mt < 4; mt++)
#pragma unroll
      for (int nt = 0; nt < 4; nt++)
#pragma unroll
        for (int r = 0; r < 4; r++) {
          int ml = wm * 64 + mt * 16 + lg * 4 + r;
          int nl = wn * 64 + nt * 16 + lr;
          smem[nl * 136 + ml] = (bf16_t)(acc[mt][nt][r] + bn[nt]);
        }
    __syncthreads();
    const int b = m0 >> 11, sbase = m0 & 2047;
#pragma unroll
    for (int c = 0; c < 8; c++) {
      int ci = c * 256 + tid;
      int dl = ci >> 4, sc2 = ci & 15;
      int n = n0 + dl, h = n >> 6, hd = n & 63;
      bf16x8 v = *reinterpret_cast<const bf16x8*>(smem + dl * 136 + sc2 * 8);
      *reinterpret_cast<bf16x8*>(out + ((size_t)((b * H_ + h) << 6) + hd) * S_ + sbase + sc2 * 8) = v;
    }
  }
}

// ---- causal flash attention (unchanged from R5) ------------------------------
// 256 threads = 4 waves; QBLK=64; block handles q-tile pair {p, 31-p}.
// 3-buffer LDS ring, 2 tiles prefetched ahead, counted vmcnt(8) + raw s_barrier.
__global__ __launch_bounds__(256) void attn_k(const bf16_t* __restrict__ qh,
                                              const bf16_t* __restrict__ kh,
                                              const bf16_t* __restrict__ vt,
                                              bf16_t* __restrict__ attn) {
  __shared__ bf16_t kbuf[3][4096];
  __shared__ bf16_t vbuf[3][4096];

  const int tid = threadIdx.x, w = tid >> 6, l = tid & 63;
  const int lr = l & 15, lg = l >> 4;

  const int ib = (int)blockIdx.y * 16 + (int)blockIdx.x;  // [0,1024)
  const int xcd = ib & 7, slot = ib >> 3;
  const int bh = xcd * 8 + (slot & 7);
  const int pr = slot >> 3;
  const int b = bh >> 4, h = bh & 15;

  const int zr0 = tid >> 3, kc = tid & 7;
  const int sks = kc ^ (zr0 & 7);
  const int kprow0 = ((zr0 >> 5) & 1) * 32 + ((zr0 >> 2) & 3) * 8 + ((zr0 >> 4) & 1) * 4 + (zr0 & 3);
  const int zr1 = 32 + zr0;
  const int kprow1 = ((zr1 >> 5) & 1) * 32 + ((zr1 >> 2) & 3) * 8 + ((zr1 >> 4) & 1) * 4 + (zr1 & 3);
  const bf16_t* kbase0 = kh + ((size_t)bh * S_ + kprow0) * HD_ + sks * 8;
  const bf16_t* kbase1 = kh + ((size_t)bh * S_ + kprow1) * HD_ + sks * 8;
  const bf16_t* vbase0 = vt + ((size_t)bh * HD_ + zr0) * S_ + sks * 8;
  const bf16_t* vbase1 = vt + ((size_t)bh * HD_ + zr1) * S_ + sks * 8;

  const int xs7 = lr & 7;
  const int koffA = lr * 64 + ((lg ^ xs7) << 3);
  const int koffB = lr * 64 + (((lg ^ xs7) ^ 4) << 3);
  const int rowlim = w * 16 + lr;
  const int wsl = w * 512;

  bf16x8 ones;
#pragma unroll
  for (int i = 0; i < 8; i++) ones[i] = (bf16_t)1.0f;

  for (int half = 0; half < 2; half++) {
    const int qt = half ? (31 - pr) : pr;
    const int q0 = qt * 64 + w * 16;

    const bf16_t* qp = qh + ((size_t)bh * S_ + q0 + lr) * HD_ + lg * 8;
    bf16x8 qf0 = *(const bf16x8*)qp;
    bf16x8 qf1 = *(const bf16x8*)(qp + 32);

    float mi = -1e30f;
    f32x4 o[4], os;
#pragma unroll
    for (int nt = 0; nt < 4; nt++) {
      f32x4 z = {0.f, 0.f, 0.f, 0.f};
      o[nt] = z;
    }
    {
      f32x4 z = {0.f, 0.f, 0.f, 0.f};
      os = z;
    }

    const bf16_t *ks0 = kbase0, *ks1 = kbase1, *vs0 = vbase0, *vs1 = vbase1;
    int jsrc = 0;

#define ISSUE_STAGE(bi)                                        \
    do {                                                       \
      gload_lds16(ks0, &kbuf[bi][wsl]);                        \
      gload_lds16(ks1, &kbuf[bi][wsl + 2048]);                 \
      gload_lds16(vs0, &vbuf[bi][wsl]);                        \
      gload_lds16(vs1, &vbuf[bi][wsl + 2048]);                 \
      if (jsrc < qt) {                                         \
        ks0 += 64 * HD_; ks1 += 64 * HD_; vs0 += 64; vs1 += 64; \
        jsrc++;                                                \
      }                                                        \
    } while (0)

    ISSUE_STAGE(0);
    ISSUE_STAGE(1);
    asm volatile("s_waitcnt vmcnt(4)" ::: "memory");
    __builtin_amdgcn_s_barrier();
    __builtin_amdgcn_sched_barrier(0);

    int cidx = 0, c2 = 2;
    for (int jt = 0; jt <= qt; jt++) {
      ISSUE_STAGE(c2);
      asm volatile("s_waitcnt vmcnt(8)" ::: "memory");
      __builtin_amdgcn_s_barrier();
      __builtin_amdgcn_sched_barrier(0);

      const bf16_t* kt = kbuf[cidx];
      const bf16_t* vb = vbuf[cidx];
      f32x4 s[4];
      __builtin_amdgcn_s_setprio(1);
#pragma unroll
      for (int nt = 0; nt < 4; nt++) {
        bf16x8 kf0 = *(const bf16x8*)(kt + koffA + nt * 1024);
        bf16x8 kf1 = *(const bf16x8*)(kt + koffB + nt * 1024);
        f32x4 a = {0.f, 0.f, 0.f, 0.f};
        a = MFMA(kf0, qf0, a);
        a = MFMA(kf1, qf1, a);
        s[nt] = a;
      }
      __builtin_amdgcn_s_setprio(0);
      if (jt == qt) {
#pragma unroll
        for (int nt = 0; nt < 4; nt++) {
          int kvb = ((nt >> 1) << 5) + ((nt & 1) << 2) + lg * 8;
#pragma unroll
          for (int r = 0; r < 4; r++)
            if (kvb + r > rowlim) s[nt][r] = -1e30f;
        }
      }
      float m0 = max3f(s[0][0], s[0][1], s[0][2]);
      float m1 = max3f(s[0][3], s[1][0], s[1][1]);
      float m2 = max3f(s[1][2], s[1][3], s[2][0]);
      float m3 = max3f(s[2][1], s[2][2], s[2][3]);
      float m4 = max3f(s[3][0], s[3][1], s[3][2]);
      float mx = fmaxf(max3f(m0, m1, m2), max3f(m3, m4, s[3][3]));
      mx = fmaxf(mx, __shfl_xor(mx, 16));
      mx = fmaxf(mx, __shfl_xor(mx, 32));
      if (!__all(mx <= mi + 8.0f)) {
        float mn = fmaxf(mi, mx);
        float al = __builtin_amdgcn_exp2f((mi - mn) * LOG2E);
        mi = mn;
#pragma unroll
        for (int r = 0; r < 4; r++) {
          float alr = __shfl(al, lg * 4 + r);
          o[0][r] *= alr; o[1][r] *= alr; o[2][r] *= alr; o[3][r] *= alr;
          os[r] *= alr;
        }
      }
      const float msc = mi * LOG2E;
#pragma unroll
      for (int nt = 0; nt < 4; nt++)
#pragma unroll
        for (int r = 0; r < 4; r++)
          s[nt][r] = __builtin_amdgcn_exp2f(s[nt][r] * LOG2E - msc);
      uint32_t pk[8];
#pragma unroll
      for (int nt = 0; nt < 4; nt++) {
        bf16x2_t plo = {(bf16_t)s[nt][0], (bf16_t)s[nt][1]};
        bf16x2_t phi = {(bf16_t)s[nt][2], (bf16_t)s[nt][3]};
        pk[nt * 2] = __builtin_bit_cast(uint32_t, plo);
        pk[nt * 2 + 1] = __builtin_bit_cast(uint32_t, phi);
      }
      i32x4 w0 = {(int)pk[0], (int)pk[1], (int)pk[2], (int)pk[3]};
      i32x4 w1 = {(int)pk[4], (int)pk[5], (int)pk[6], (int)pk[7]};
      bf16x8 pa0 = __builtin_bit_cast(bf16x8, w0);
      bf16x8 pa1 = __builtin_bit_cast(bf16x8, w1);
      __builtin_amdgcn_s_setprio(1);
#pragma unroll
      for (int ntd = 0; ntd < 4; ntd++) {
        bf16x8 vf0 = *(const bf16x8*)(vb + koffA + ntd * 1024);
        bf16x8 vf1 = *(const bf16x8*)(vb + koffB + ntd * 1024);
        o[ntd] = MFMA(pa0, vf0, o[ntd]);
        o[ntd] = MFMA(pa1, vf1, o[ntd]);
      }
      os = MFMA(pa0, ones, os);
      os = MFMA(pa1, ones, os);
      __builtin_amdgcn_s_setprio(0);

      __builtin_amdgcn_sched_barrier(0);
      __builtin_amdgcn_s_barrier();
      __builtin_amdgcn_sched_barrier(0);
      cidx = (cidx == 2) ? 0 : cidx + 1;
      c2 = (c2 == 2) ? 0 : c2 + 1;
    }
#undef ISSUE_STAGE
#pragma unroll
    for (int r = 0; r < 4; r++) {
      float rinv = 1.f / os[r];
      int srw = q0 + lg * 4 + r;
#pragma unroll
      for (int ntd = 0; ntd < 4; ntd++)
        attn[((size_t)(b * S_ + srw)) * D_ + h * 64 + ntd * 16 + lr] =
            (bf16_t)(o[ntd][r] * rinv);
    }
  }
}

extern "C" void kernel_launch(void* const* d_in, const int* in_sizes, int n_in,
                              void* d_out, int out_size, void* d_ws, size_t ws_size,
                              hipStream_t stream) {
  (void)in_sizes; (void)n_in; (void)out_size; (void)ws_size;
  const float* q  = (const float*)d_in[0];
  const float* k  = (const float*)d_in[1];
  const float* v  = (const float*)d_in[2];
  // d_in[3] = mask: causal triu, hard-coded in attn_k
  const float* Wq = (const float*)d_in[4];
  const float* bq = (const float*)d_in[5];
  const float* Wk = (const float*)d_in[6];
  const float* bk = (const float*)d_in[7];
  const float* Wv = (const float*)d_in[8];
  const float* bv = (const float*)d_in[9];
  const float* Wo = (const float*)d_in[10];
  const float* bo = (const float*)d_in[11];

  char* ws = (char*)d_ws;
  bf16_t* wt0  = (bf16_t*)(ws + (0ull << 20));   // 4 x 2MB transposed weights
  bf16_t* wto  = (bf16_t*)(ws + (6ull << 20));
  bf16_t* qkvb = (bf16_t*)(ws + (8ull << 20));   // bf16 q/k/v, 3 x 16MB
  bf16_t* qhb  = (bf16_t*)(ws + (56ull << 20));  // Qh/Kh/VT, 3 x 16MB
  bf16_t* khb  = (bf16_t*)(ws + (72ull << 20));
  bf16_t* vtb  = (bf16_t*)(ws + (88ull << 20));
  bf16_t* atb  = (bf16_t*)(ws + (8ull << 20));   // aliases qkvb (dead by then)

  dim3 tb(256);
  wt_kernel<<<dim3(32, 32, 4), tb, 0, stream>>>(Wq, Wk, Wv, Wo, wt0);
  conv_kernel<<<dim3(4096, 1, 3), tb, 0, stream>>>(q, k, v, qkvb);
  mm_kernel<true><<<dim3(8, 64, 3), tb, 0, stream>>>(qkvb, wt0, bq, bk, bv, qhb);
  attn_k<<<dim3(16, 64), tb, 0, stream>>>(qhb, khb, vtb, atb);
  mm_kernel<false><<<dim3(8, 64), tb, 0, stream>>>(atb, wto, bo, nullptr, nullptr, d_out);
}

// Round 7
// 178.914 us; speedup vs baseline: 3.4406x; 1.0434x over previous
//
#include <hip/hip_runtime.h>
#include <hip/hip_bf16.h>
#include <stdint.h>

#define B_ 4
#define S_ 2048
#define D_ 1024
#define H_ 16
#define HD_ 64

typedef __bf16 bf16_t;
typedef __bf16 bf16x8 __attribute__((ext_vector_type(8)));
typedef __bf16 bf16x2_t __attribute__((ext_vector_type(2)));
typedef float f32x4 __attribute__((ext_vector_type(4)));
typedef int i32x4 __attribute__((ext_vector_type(4)));

#define MFMA(a, b, c) __builtin_amdgcn_mfma_f32_16x16x32_bf16((a), (b), (c), 0, 0, 0)
#define LOG2E 1.44269504088896340736f

__device__ __forceinline__ void gload_lds16(const void* g, void* l) {
  __builtin_amdgcn_global_load_lds(
      (const __attribute__((address_space(1))) uint32_t*)g,
      (__attribute__((address_space(3))) uint32_t*)l, 16, 0, 0);
}

__device__ __forceinline__ float max3f(float a, float b, float c) {
  float d;
  asm("v_max3_f32 %0, %1, %2, %3" : "=v"(d) : "v"(a), "v"(b), "v"(c));
  return d;
}

// ---- fused weight transpose + convert: WT[n][k] = bf16(W[k][n]), 4 weights --
__global__ __launch_bounds__(256) void wt_kernel(const float* __restrict__ Wq,
                                                 const float* __restrict__ Wk,
                                                 const float* __restrict__ Wv,
                                                 const float* __restrict__ Wo,
                                                 bf16_t* __restrict__ wt0) {
  __shared__ float t[32][33];
  const int z = blockIdx.z;
  const float* w_ = z == 0 ? Wq : (z == 1 ? Wk : (z == 2 ? Wv : Wo));
  bf16_t* wt = wt0 + (size_t)z * (1u << 20);
  const int tx = threadIdx.x & 31, ty = threadIdx.x >> 5;
  const int n0 = blockIdx.x * 32, k0 = blockIdx.y * 32;
#pragma unroll
  for (int i = 0; i < 4; i++)
    t[ty + i * 8][tx] = w_[(size_t)(k0 + ty + i * 8) * D_ + n0 + tx];
  __syncthreads();
#pragma unroll
  for (int i = 0; i < 4; i++)
    wt[(size_t)(n0 + ty + i * 8) * D_ + k0 + tx] = (bf16_t)t[tx][ty + i * 8];
}

// ---- q/k/v f32 -> bf16 (flat, same layout): one dispatch, z picks source ---
__global__ __launch_bounds__(256) void conv_kernel(const float* __restrict__ q,
                                                   const float* __restrict__ k,
                                                   const float* __restrict__ v,
                                                   bf16_t* __restrict__ out) {
  const int z = blockIdx.z;
  const float* src = z == 0 ? q : (z == 1 ? k : v);
  bf16_t* dst = out + (size_t)z * 8388608u;
  const size_t i = ((size_t)blockIdx.x * 256 + threadIdx.x) * 8;
  float4 x0 = *(const float4*)(src + i);
  float4 x1 = *(const float4*)(src + i + 4);
  bf16x8 vv;
  vv[0] = (bf16_t)x0.x; vv[1] = (bf16_t)x0.y; vv[2] = (bf16_t)x0.z; vv[3] = (bf16_t)x0.w;
  vv[4] = (bf16_t)x1.x; vv[5] = (bf16_t)x1.y; vv[6] = (bf16_t)x1.z; vv[7] = (bf16_t)x1.w;
  *(bf16x8*)(dst + i) = vv;
}

// ---- ring GEMM: C[8192x1024] = A(bf16) @ WT^T + b ---------------------------
// 2-buffer LDS ring, tile j+2 staged after the WAR barrier, counted vmcnt(8).
// QKV=true: grid.z = 0(Q)/1(K)/2(V), bf16 head-split outputs (V transposed).
// QKV=false: single slice, f32 [m][n] + bias (final projection).
template <bool QKV>
__global__ __launch_bounds__(256) void mm_kernel(const bf16_t* __restrict__ A0,
                                                 const bf16_t* __restrict__ wt0,
                                                 const float* __restrict__ b0,
                                                 const float* __restrict__ b1,
                                                 const float* __restrict__ b2,
                                                 void* __restrict__ out0) {
  __shared__ bf16_t smem[32768];  // 2 bufs x (A[128][64] + B[128][64])

  const int z = QKV ? blockIdx.z : 0;
  const bf16_t* A = A0 + (size_t)z * 8388608u;
  const bf16_t* WT = wt0 + (size_t)z * 1048576u;
  const float* bias = QKV ? (z == 0 ? b0 : (z == 1 ? b1 : b2)) : b0;

  const int tid = threadIdx.x;
  const int w = tid >> 6, l = tid & 63;
  const int lr = l & 15, lg = l >> 4;
  const int wm = w >> 1, wn = w & 1;
  // XCD-chunked swizzle: 8 consecutive hw blocks -> 8 m-panels on one XCD
  const int ib = (int)blockIdx.y * 8 + (int)blockIdx.x;  // 512 blocks/slice
  const int swz = (ib & 7) * 64 + (ib >> 3);
  const int m0 = (swz >> 3) * 128, n0 = (swz & 7) * 128;

  // hoisted staging addresses: chunk c covers rows c*32 + (tid>>3)
  const int row0 = tid >> 3;
  const int ks = (tid & 7) ^ (row0 & 7);  // (c*32+row0)&7 == row0&7
  const bf16_t* aS = A + (size_t)(m0 + row0) * 1024 + ks * 8;
  const bf16_t* bS = WT + (size_t)(n0 + row0) * 1024 + ks * 8;
  const int wsl = w * 512;  // wave-uniform LDS chunk base (elements)

  f32x4 acc[4][4];
#pragma unroll
  for (int mt = 0; mt < 4; mt++)
#pragma unroll
    for (int nt = 0; nt < 4; nt++) {
      f32x4 zz = {0.f, 0.f, 0.f, 0.f};
      acc[mt][nt] = zz;
    }

// stage tile (kt = tile*64) into buffer bi: 8 gload_lds per thread
#define STAGE(bi, kt)                                                   \
  do {                                                                  \
    bf16_t* ad = smem + (bi) * 16384 + wsl;                             \
    bf16_t* bd = smem + (bi) * 16384 + 8192 + wsl;                      \
    _Pragma("unroll") for (int c = 0; c < 4; c++) {                     \
      gload_lds16(bS + (size_t)c * 32768 + (kt), bd + c * 2048);        \
      gload_lds16(aS + (size_t)c * 32768 + (kt), ad + c * 2048);        \
    }                                                                   \
  } while (0)

  // prologue: tiles 0 and 1
  STAGE(0, 0);
  STAGE(1, 64);
  asm volatile("s_waitcnt vmcnt(8)" ::: "memory");  // stage(0) landed
  __builtin_amdgcn_s_barrier();
  __builtin_amdgcn_sched_barrier(0);

  int buf = 0;
  for (int jt = 0; jt < 16; ++jt) {
    const bf16_t* alds = smem + buf * 16384;
    const bf16_t* blds = alds + 8192;
#pragma unroll
    for (int kk = 0; kk < 2; kk++) {
      bf16x8 af[4], bfr[4];
#pragma unroll
      for (int mt = 0; mt < 4; mt++) {
        int row = wm * 64 + mt * 16 + lr;
        int kc = kk * 4 + lg;
        af[mt] = *reinterpret_cast<const bf16x8*>(alds + row * 64 + ((kc ^ (row & 7)) * 8));
      }
#pragma unroll
      for (int nt = 0; nt < 4; nt++) {
        int row = wn * 64 + nt * 16 + lr;
        int kc = kk * 4 + lg;
        bfr[nt] = *reinterpret_cast<const bf16x8*>(blds + row * 64 + ((kc ^ (row & 7)) * 8));
      }
#pragma unroll
      for (int mt = 0; mt < 4; mt++)
#pragma unroll
        for (int nt = 0; nt < 4; nt++)
          acc[mt][nt] = MFMA(af[mt], bfr[nt], acc[mt][nt]);
    }
    if (jt == 15) break;
    __builtin_amdgcn_sched_barrier(0);
    __builtin_amdgcn_s_barrier();  // WAR: all readers done with buf
    __builtin_amdgcn_sched_barrier(0);
    const int tn = (jt + 2 < 16) ? jt + 2 : 15;  // dead re-stage keeps count uniform
    STAGE(buf, tn * 64);
    asm volatile("s_waitcnt vmcnt(8)" ::: "memory");  // stage(jt+1) landed
    __builtin_amdgcn_s_barrier();                     // RAW
    __builtin_amdgcn_sched_barrier(0);
    buf ^= 1;
  }
#undef STAGE

  float bn[4];
#pragma unroll
  for (int nt = 0; nt < 4; nt++) bn[nt] = bias[n0 + wn * 64 + nt * 16 + lr];

  if (!QKV) {
    float* out = (float*)out0;
#pragma unroll
    for (int mt = 0; mt < 4; mt++)
#pragma unroll
      for (int nt = 0; nt < 4; nt++)
#pragma unroll
        for (int r = 0; r < 4; r++) {
          int m = m0 + wm * 64 + mt * 16 + lg * 4 + r;
          int n = n0 + wn * 64 + nt * 16 + lr;
          out[(size_t)m * D_ + n] = acc[mt][nt][r] + bn[nt];
        }
  } else if (z != 2) {
    bf16_t* out = (bf16_t*)out0 + (size_t)z * 8388608u;
    const float sc = z == 0 ? 0.125f : 1.0f;  // 1/sqrt(HD) exact in bf16
#pragma unroll
    for (int mt = 0; mt < 4; mt++)
#pragma unroll
      for (int nt = 0; nt < 4; nt++)
#pragma unroll
        for (int r = 0; r < 4; r++) {
          int m = m0 + wm * 64 + mt * 16 + lg * 4 + r;
          int n = n0 + wn * 64 + nt * 16 + lr;
          float v = (acc[mt][nt][r] + bn[nt]) * sc;
          int b = m >> 11, s = m & 2047, h = n >> 6, hd = n & 63;
          out[(((size_t)(b * H_ + h) * S_ + s) << 6) + hd] = (bf16_t)v;
        }
  } else {  // V: transpose in LDS, write VT[(b*16+h)][hd][s]
    bf16_t* out = (bf16_t*)out0 + (size_t)z * 8388608u;
    __syncthreads();  // drains vmcnt (incl. dead re-stage) + all waves done
#pragma unroll
    for (int mt = 0; mt < 4; mt++)
#pragma unroll
      for (int nt = 0; nt < 4; nt++)
#pragma unroll
        for (int r = 0; r < 4; r++) {
          int ml = wm * 64 + mt * 16 + lg * 4 + r;
          int nl = wn * 64 + nt * 16 + lr;
          smem[nl * 136 + ml] = (bf16_t)(acc[mt][nt][r] + bn[nt]);
        }
    __syncthreads();
    const int b = m0 >> 11, sbase = m0 & 2047;
#pragma unroll
    for (int c = 0; c < 8; c++) {
      int ci = c * 256 + tid;
      int dl = ci >> 4, sc2 = ci & 15;
      int n = n0 + dl, h = n >> 6, hd = n & 63;
      bf16x8 v = *reinterpret_cast<const bf16x8*>(smem + dl * 136 + sc2 * 8);
      *reinterpret_cast<bf16x8*>(out + ((size_t)((b * H_ + h) << 6) + hd) * S_ + sbase + sc2 * 8) = v;
    }
  }
}

// ---- causal flash attention ------------------------------------------------
// 256 threads = 4 waves; QBLK=64; block handles q-tile pair {p, 31-p}.
// 2-buffer LDS ring (32 KB -> 5 blocks/CU cap), 1 tile prefetched ahead,
// counted vmcnt(4) + raw s_barrier: stage(j+1) stays in flight across both
// barriers, never drained to 0 in the loop. One vmcnt(0) per half boundary
// orders the dead tail re-stage against the next prologue's LDS DMA writes.
__global__ __launch_bounds__(256) void attn_k(const bf16_t* __restrict__ qh,
                                              const bf16_t* __restrict__ kh,
                                              const bf16_t* __restrict__ vt,
                                              bf16_t* __restrict__ attn) {
  __shared__ bf16_t kbuf[2][4096];
  __shared__ bf16_t vbuf[2][4096];

  const int tid = threadIdx.x, w = tid >> 6, l = tid & 63;
  const int lr = l & 15, lg = l >> 4;

  // XCD mapping: ib&7 = XCD; each XCD serves 8 bh (K/V = 4MB = one L2)
  const int ib = (int)blockIdx.y * 16 + (int)blockIdx.x;  // [0,1024)
  const int xcd = ib & 7, slot = ib >> 3;
  const int bh = xcd * 8 + (slot & 7);
  const int pr = slot >> 3;  // pair index 0..15
  const int b = bh >> 4, h = bh & 15;

  // staging geometry: chunk i in {0,1}; slot-row zr_i = i*32 + tid>>3
  const int zr0 = tid >> 3, kc = tid & 7;
  const int sks = kc ^ (zr0 & 7);
  const int kprow0 = ((zr0 >> 5) & 1) * 32 + ((zr0 >> 2) & 3) * 8 + ((zr0 >> 4) & 1) * 4 + (zr0 & 3);
  const int zr1 = 32 + zr0;
  const int kprow1 = ((zr1 >> 5) & 1) * 32 + ((zr1 >> 2) & 3) * 8 + ((zr1 >> 4) & 1) * 4 + (zr1 & 3);
  const bf16_t* kbase0 = kh + ((size_t)bh * S_ + kprow0) * HD_ + sks * 8;
  const bf16_t* kbase1 = kh + ((size_t)bh * S_ + kprow1) * HD_ + sks * 8;
  const bf16_t* vbase0 = vt + ((size_t)bh * HD_ + zr0) * S_ + sks * 8;
  const bf16_t* vbase1 = vt + ((size_t)bh * HD_ + zr1) * S_ + sks * 8;

  const int xs7 = lr & 7;
  const int koffA = lr * 64 + ((lg ^ xs7) << 3);
  const int koffB = lr * 64 + (((lg ^ xs7) ^ 4) << 3);
  const int rowlim = w * 16 + lr;
  const int wsl = w * 512;  // wave staging slice

  bf16x8 ones;
#pragma unroll
  for (int i = 0; i < 8; i++) ones[i] = (bf16_t)1.0f;

  for (int half = 0; half < 2; half++) {
    const int qt = half ? (31 - pr) : pr;
    const int q0 = qt * 64 + w * 16;

    const bf16_t* qp = qh + ((size_t)bh * S_ + q0 + lr) * HD_ + lg * 8;
    bf16x8 qf0 = *(const bf16x8*)qp;
    bf16x8 qf1 = *(const bf16x8*)(qp + 32);

    float mi = -1e30f;
    f32x4 o[4], os;
#pragma unroll
    for (int nt = 0; nt < 4; nt++) {
      f32x4 z = {0.f, 0.f, 0.f, 0.f};
      o[nt] = z;
    }
    {
      f32x4 z = {0.f, 0.f, 0.f, 0.f};
      os = z;
    }

    const bf16_t *ks0 = kbase0, *ks1 = kbase1, *vs0 = vbase0, *vs1 = vbase1;
    int jsrc = 0;

    // issue one tile's staging (4 loads) to the given per-wave slices; clamp
    // source advance at tile qt (dead re-stages keep vmcnt accounting uniform)
#define ISSUE_STAGE(kd, vd)                                     \
    do {                                                        \
      gload_lds16(ks0, (kd));                                   \
      gload_lds16(ks1, (kd) + 2048);                            \
      gload_lds16(vs0, (vd));                                   \
      gload_lds16(vs1, (vd) + 2048);                            \
      if (jsrc < qt) {                                          \
        ks0 += 64 * HD_; ks1 += 64 * HD_; vs0 += 64; vs1 += 64; \
        jsrc++;                                                 \
      }                                                         \
    } while (0)

    // order prev half's dead re-stage before overwriting buf0 (LDS DMA writes
    // from different loads to the same address are not otherwise ordered)
    asm volatile("s_waitcnt vmcnt(0)" ::: "memory");

    // double-buffer pointers: read base (whole buf) + write slice (other buf)
    const bf16_t *rK = kbuf[0], *rV = vbuf[0];
    const bf16_t *rKn = kbuf[1], *rVn = vbuf[1];
    bf16_t *wK = &kbuf[1][wsl], *wV = &vbuf[1][wsl];
    bf16_t *wKn = &kbuf[0][wsl], *wVn = &vbuf[0][wsl];

    ISSUE_STAGE(wKn, wVn);  // tile 0 -> buf0

    for (int jt = 0; jt <= qt; jt++) {
      ISSUE_STAGE(wK, wV);  // tile jt+1 (clamped) -> other buffer
      asm volatile("s_waitcnt vmcnt(4)" ::: "memory");  // stage(jt) landed
      __builtin_amdgcn_s_barrier();                     // everyone's landed
      __builtin_amdgcn_sched_barrier(0);

      f32x4 s[4];
      __builtin_amdgcn_s_setprio(1);
#pragma unroll
      for (int nt = 0; nt < 4; nt++) {
        bf16x8 kf0 = *(const bf16x8*)(rK + koffA + nt * 1024);
        bf16x8 kf1 = *(const bf16x8*)(rK + koffB + nt * 1024);
        f32x4 a = {0.f, 0.f, 0.f, 0.f};
        a = MFMA(kf0, qf0, a);  // swapped: K as A-operand
        a = MFMA(kf1, qf1, a);
        s[nt] = a;
      }
      __builtin_amdgcn_s_setprio(0);
      if (jt == qt) {  // diagonal tile: causal mask, kv = pi(nt,lg,r)
#pragma unroll
        for (int nt = 0; nt < 4; nt++) {
          int kvb = ((nt >> 1) << 5) + ((nt & 1) << 2) + lg * 8;
#pragma unroll
          for (int r = 0; r < 4; r++)
            if (kvb + r > rowlim) s[nt][r] = -1e30f;
        }
      }
      // row max: v_max3 tree + cross-copy reduce
      float m0 = max3f(s[0][0], s[0][1], s[0][2]);
      float m1 = max3f(s[0][3], s[1][0], s[1][1]);
      float m2 = max3f(s[1][2], s[1][3], s[2][0]);
      float m3 = max3f(s[2][1], s[2][2], s[2][3]);
      float m4 = max3f(s[3][0], s[3][1], s[3][2]);
      float mx = fmaxf(max3f(m0, m1, m2), max3f(m3, m4, s[3][3]));
      mx = fmaxf(mx, __shfl_xor(mx, 16));
      mx = fmaxf(mx, __shfl_xor(mx, 32));
      // T13 defer-max
      if (!__all(mx <= mi + 8.0f)) {
        float mn = fmaxf(mi, mx);
        float al = __builtin_amdgcn_exp2f((mi - mn) * LOG2E);
        mi = mn;
#pragma unroll
        for (int r = 0; r < 4; r++) {
          float alr = __shfl(al, lg * 4 + r);
          o[0][r] *= alr; o[1][r] *= alr; o[2][r] *= alr; o[3][r] *= alr;
          os[r] *= alr;
        }
      }
      const float msc = mi * LOG2E;
#pragma unroll
      for (int nt = 0; nt < 4; nt++)
#pragma unroll
        for (int r = 0; r < 4; r++)
          s[nt][r] = __builtin_amdgcn_exp2f(s[nt][r] * LOG2E - msc);
      // P -> PA fragments: pure in-lane packs
      uint32_t pk[8];
#pragma unroll
      for (int nt = 0; nt < 4; nt++) {
        bf16x2_t plo = {(bf16_t)s[nt][0], (bf16_t)s[nt][1]};
        bf16x2_t phi = {(bf16_t)s[nt][2], (bf16_t)s[nt][3]};
        pk[nt * 2] = __builtin_bit_cast(uint32_t, plo);
        pk[nt * 2 + 1] = __builtin_bit_cast(uint32_t, phi);
      }
      i32x4 w0 = {(int)pk[0], (int)pk[1], (int)pk[2], (int)pk[3]};
      i32x4 w1 = {(int)pk[4], (int)pk[5], (int)pk[6], (int)pk[7]};
      bf16x8 pa0 = __builtin_bit_cast(bf16x8, w0);
      bf16x8 pa1 = __builtin_bit_cast(bf16x8, w1);
      __builtin_amdgcn_s_setprio(1);
#pragma unroll
      for (int ntd = 0; ntd < 4; ntd++) {
        bf16x8 vf0 = *(const bf16x8*)(rV + koffA + ntd * 1024);
        bf16x8 vf1 = *(const bf16x8*)(rV + koffB + ntd * 1024);
        o[ntd] = MFMA(pa0, vf0, o[ntd]);
        o[ntd] = MFMA(pa1, vf1, o[ntd]);
      }
      os = MFMA(pa0, ones, os);  // row-sum of P accumulates li in o-layout
      os = MFMA(pa1, ones, os);
      __builtin_amdgcn_s_setprio(0);

      __builtin_amdgcn_sched_barrier(0);
      __builtin_amdgcn_s_barrier();  // WAR: reads done before buf reuse
      __builtin_amdgcn_sched_barrier(0);
      // swap read/write buffer pointers (phi nodes, no per-tile math)
      { const bf16_t* t = rK; rK = rKn; rKn = t; t = rV; rV = rVn; rVn = t; }
      { bf16_t* t = wK; wK = wKn; wKn = t; t = wV; wV = wVn; wVn = t; }
    }
#undef ISSUE_STAGE
    // epilogue: attn[b][s][h*64+hd]
#pragma unroll
    for (int r = 0; r < 4; r++) {
      float rinv = 1.f / os[r];
      int srw = q0 + lg * 4 + r;
#pragma unroll
      for (int ntd = 0; ntd < 4; ntd++)
        attn[((size_t)(b * S_ + srw)) * D_ + h * 64 + ntd * 16 + lr] =
            (bf16_t)(o[ntd][r] * rinv);
    }
  }
}

extern "C" void kernel_launch(void* const* d_in, const int* in_sizes, int n_in,
                              void* d_out, int out_size, void* d_ws, size_t ws_size,
                              hipStream_t stream) {
  (void)in_sizes; (void)n_in; (void)out_size; (void)ws_size;
  const float* q  = (const float*)d_in[0];
  const float* k  = (const float*)d_in[1];
  const float* v  = (const float*)d_in[2];
  // d_in[3] = mask: causal triu, hard-coded in attn_k
  const float* Wq = (const float*)d_in[4];
  const float* bq = (const float*)d_in[5];
  const float* Wk = (const float*)d_in[6];
  const float* bk = (const float*)d_in[7];
  const float* Wv = (const float*)d_in[8];
  const float* bv = (const float*)d_in[9];
  const float* Wo = (const float*)d_in[10];
  const float* bo = (const float*)d_in[11];

  char* ws = (char*)d_ws;
  bf16_t* wt0  = (bf16_t*)(ws + (0ull << 20));   // 4 x 2MB transposed weights
  bf16_t* wto  = (bf16_t*)(ws + (6ull << 20));
  bf16_t* qkvb = (bf16_t*)(ws + (8ull << 20));   // bf16 q/k/v, 3 x 16MB
  bf16_t* qhb  = (bf16_t*)(ws + (56ull << 20));  // Qh/Kh/VT, 3 x 16MB
  bf16_t* khb  = (bf16_t*)(ws + (72ull << 20));
  bf16_t* vtb  = (bf16_t*)(ws + (88ull << 20));
  bf16_t* atb  = (bf16_t*)(ws + (8ull << 20));   // aliases qkvb (dead by then)

  dim3 tb(256);
  wt_kernel<<<dim3(32, 32, 4), tb, 0, stream>>>(Wq, Wk, Wv, Wo, wt0);
  conv_kernel<<<dim3(4096, 1, 3), tb, 0, stream>>>(q, k, v, qkvb);
  mm_kernel<true><<<dim3(8, 64, 3), tb, 0, stream>>>(qkvb, wt0, bq, bk, bv, qhb);
  attn_k<<<dim3(16, 64), tb, 0, stream>>>(qhb, khb, vtb, atb);
  mm_kernel<false><<<dim3(8, 64), tb, 0, stream>>>(atb, wto, bo, nullptr, nullptr, d_out);
}

// Round 9
// 171.100 us; speedup vs baseline: 3.5977x; 1.0457x over previous
//
#include <hip/hip_runtime.h>
#include <hip/hip_bf16.h>
#include <stdint.h>

#define B_ 4
#define S_ 2048
#define D_ 1024
#define H_ 16
#define HD_ 64

typedef __bf16 bf16_t;
typedef __bf16 bf16x8 __attribute__((ext_vector_type(8)));
typedef __bf16 bf16x2_t __attribute__((ext_vector_type(2)));
typedef float f32x4 __attribute__((ext_vector_type(4)));
typedef int i32x4 __attribute__((ext_vector_type(4)));

#define MFMA(a, b, c) __builtin_amdgcn_mfma_f32_16x16x32_bf16((a), (b), (c), 0, 0, 0)
#define LOG2E 1.44269504088896340736f

__device__ __forceinline__ void gload_lds16(const void* g, void* l) {
  __builtin_amdgcn_global_load_lds(
      (const __attribute__((address_space(1))) uint32_t*)g,
      (__attribute__((address_space(3))) uint32_t*)l, 16, 0, 0);
}

__device__ __forceinline__ float max3f(float a, float b, float c) {
  float d;
  asm("v_max3_f32 %0, %1, %2, %3" : "=v"(d) : "v"(a), "v"(b), "v"(c));
  return d;
}

// ---- fused weight transpose + convert: WT[n][k] = bf16(W[k][n]), 4 weights --
__global__ __launch_bounds__(256) void wt_kernel(const float* __restrict__ Wq,
                                                 const float* __restrict__ Wk,
                                                 const float* __restrict__ Wv,
                                                 const float* __restrict__ Wo,
                                                 bf16_t* __restrict__ wt0) {
  __shared__ float t[32][33];
  const int z = blockIdx.z;
  const float* w_ = z == 0 ? Wq : (z == 1 ? Wk : (z == 2 ? Wv : Wo));
  bf16_t* wt = wt0 + (size_t)z * (1u << 20);
  const int tx = threadIdx.x & 31, ty = threadIdx.x >> 5;
  const int n0 = blockIdx.x * 32, k0 = blockIdx.y * 32;
#pragma unroll
  for (int i = 0; i < 4; i++)
    t[ty + i * 8][tx] = w_[(size_t)(k0 + ty + i * 8) * D_ + n0 + tx];
  __syncthreads();
#pragma unroll
  for (int i = 0; i < 4; i++)
    wt[(size_t)(n0 + ty + i * 8) * D_ + k0 + tx] = (bf16_t)t[tx][ty + i * 8];
}

// ---- QKV GEMM with fused f32->bf16 A conversion (T14 reg-staged A) ---------
// grid.z = 0(Q)/1(K)/2(V). B via global_load_lds; A via f32 reg-load +
// convert + ds_write. Counted vmcnt(12): one full stage (4 B-DMA + 8 A-loads)
// stays in flight across barriers. Loop unrolled x2 for static reg sets.
__global__ __launch_bounds__(256) void qkv_mm(const float* __restrict__ Aq,
                                              const float* __restrict__ Ak,
                                              const float* __restrict__ Av,
                                              const bf16_t* __restrict__ wt0,
                                              const float* __restrict__ b0,
                                              const float* __restrict__ b1,
                                              const float* __restrict__ b2,
                                              bf16_t* __restrict__ out0) {
  __shared__ bf16_t smem[32768];  // 2 bufs x (A[128][64] + B[128][64])

  const int z = blockIdx.z;
  const float* Af = z == 0 ? Aq : (z == 1 ? Ak : Av);
  const bf16_t* WT = wt0 + (size_t)z * 1048576u;
  const float* bias = z == 0 ? b0 : (z == 1 ? b1 : b2);
  bf16_t* out = out0 + (size_t)z * 8388608u;

  const int tid = threadIdx.x;
  const int w = tid >> 6, l = tid & 63;
  const int lr = l & 15, lg = l >> 4;
  const int wm = w >> 1, wn = w & 1;
  const int ib = (int)blockIdx.y * 8 + (int)blockIdx.x;  // 512 blocks/slice
  const int swz = (ib & 7) * 64 + (ib >> 3);
  const int m0 = (swz >> 3) * 128, n0 = (swz & 7) * 128;

  const int row0 = tid >> 3;
  const int ks = (tid & 7) ^ (row0 & 7);
  const float* aSf = Af + (size_t)(m0 + row0) * 1024 + ks * 8;
  const bf16_t* bS = WT + (size_t)(n0 + row0) * 1024 + ks * 8;
  const int wsl = w * 512;

  f32x4 acc[4][4];
#pragma unroll
  for (int mt = 0; mt < 4; mt++)
#pragma unroll
    for (int nt = 0; nt < 4; nt++) {
      f32x4 zz = {0.f, 0.f, 0.f, 0.f};
      acc[mt][nt] = zz;
    }

  float4 aLoA[4], aHiA[4], aLoB[4], aHiB[4];

#define STAGE_B(bi, kt)                                              \
  do {                                                               \
    bf16_t* bd = smem + (bi) * 16384 + 8192 + wsl;                   \
    _Pragma("unroll") for (int c = 0; c < 4; c++)                    \
        gload_lds16(bS + (size_t)c * 32768 + (kt), bd + c * 2048);   \
  } while (0)

#define LOADA(kt, Lo, Hi)                                            \
  do {                                                               \
    _Pragma("unroll") for (int c = 0; c < 4; c++) {                  \
      Lo[c] = *(const float4*)(aSf + (size_t)c * 32768 + (kt));      \
      Hi[c] = *(const float4*)(aSf + (size_t)c * 32768 + (kt) + 4);  \
    }                                                                \
  } while (0)

#define WRITEA(bi, Lo, Hi)                                           \
  do {                                                               \
    _Pragma("unroll") for (int c = 0; c < 4; c++) {                  \
      bf16x8 vv;                                                     \
      vv[0] = (bf16_t)Lo[c].x; vv[1] = (bf16_t)Lo[c].y;              \
      vv[2] = (bf16_t)Lo[c].z; vv[3] = (bf16_t)Lo[c].w;              \
      vv[4] = (bf16_t)Hi[c].x; vv[5] = (bf16_t)Hi[c].y;              \
      vv[6] = (bf16_t)Hi[c].z; vv[7] = (bf16_t)Hi[c].w;              \
      *(bf16x8*)(smem + (bi) * 16384 + c * 2048 + tid * 8) = vv;     \
    }                                                                \
  } while (0)

#define COMPUTE(bi)                                                              \
  do {                                                                           \
    const bf16_t* alds = smem + (bi) * 16384;                                    \
    const bf16_t* blds = alds + 8192;                                            \
    _Pragma("unroll") for (int kk = 0; kk < 2; kk++) {                           \
      bf16x8 af[4], bfr[4];                                                      \
      _Pragma("unroll") for (int mt = 0; mt < 4; mt++) {                         \
        int row = wm * 64 + mt * 16 + lr;                                        \
        int kc = kk * 4 + lg;                                                    \
        af[mt] = *(const bf16x8*)(alds + row * 64 + ((kc ^ (row & 7)) * 8));     \
      }                                                                          \
      _Pragma("unroll") for (int nt = 0; nt < 4; nt++) {                         \
        int row = wn * 64 + nt * 16 + lr;                                        \
        int kc = kk * 4 + lg;                                                    \
        bfr[nt] = *(const bf16x8*)(blds + row * 64 + ((kc ^ (row & 7)) * 8));    \
      }                                                                          \
      _Pragma("unroll") for (int mt = 0; mt < 4; mt++)                           \
          _Pragma("unroll") for (int nt = 0; nt < 4; nt++)                       \
              acc[mt][nt] = MFMA(af[mt], bfr[nt], acc[mt][nt]);                  \
    }                                                                            \
  } while (0)

  // prologue: stage tiles 0 and 1 (B->LDS, A->regs)
  STAGE_B(0, 0);
  LOADA(0, aLoA, aHiA);
  STAGE_B(1, 64);
  LOADA(64, aLoB, aHiB);
  asm volatile("s_waitcnt vmcnt(12)" ::: "memory");  // stage0 landed
  WRITEA(0, aLoA, aHiA);
  asm volatile("s_waitcnt lgkmcnt(0)" ::: "memory");
  __builtin_amdgcn_s_barrier();
  __builtin_amdgcn_sched_barrier(0);

  for (int jt = 0; jt < 16; jt += 2) {
    COMPUTE(0);  // tile jt
    __builtin_amdgcn_sched_barrier(0);
    __builtin_amdgcn_s_barrier();  // WAR buf0
    __builtin_amdgcn_sched_barrier(0);
    {
      const int kt2 = (jt + 2 < 16 ? jt + 2 : 15) * 64;  // dead re-stage at tail
      STAGE_B(0, kt2);
      LOADA(kt2, aLoA, aHiA);
    }
    asm volatile("s_waitcnt vmcnt(12)" ::: "memory");  // stage jt+1 landed
    WRITEA(1, aLoB, aHiB);
    asm volatile("s_waitcnt lgkmcnt(0)" ::: "memory");
    __builtin_amdgcn_s_barrier();  // RAW buf1
    __builtin_amdgcn_sched_barrier(0);
    COMPUTE(1);  // tile jt+1
    if (jt == 14) break;
    __builtin_amdgcn_sched_barrier(0);
    __builtin_amdgcn_s_barrier();  // WAR buf1
    __builtin_amdgcn_sched_barrier(0);
    {
      const int kt3 = (jt + 3) * 64;  // jt <= 12 here -> <= 960
      STAGE_B(1, kt3);
      LOADA(kt3, aLoB, aHiB);
    }
    asm volatile("s_waitcnt vmcnt(12)" ::: "memory");  // stage jt+2 landed
    WRITEA(0, aLoA, aHiA);
    asm volatile("s_waitcnt lgkmcnt(0)" ::: "memory");
    __builtin_amdgcn_s_barrier();  // RAW buf0
    __builtin_amdgcn_sched_barrier(0);
  }
#undef STAGE_B
#undef LOADA
#undef WRITEA
#undef COMPUTE

  float bn[4];
#pragma unroll
  for (int nt = 0; nt < 4; nt++) bn[nt] = bias[n0 + wn * 64 + nt * 16 + lr];

  if (z != 2) {
    const float sc = z == 0 ? 0.125f : 1.0f;  // 1/sqrt(HD) exact in bf16
#pragma unroll
    for (int mt = 0; mt < 4; mt++)
#pragma unroll
      for (int nt = 0; nt < 4; nt++)
#pragma unroll
        for (int r = 0; r < 4; r++) {
          int m = m0 + wm * 64 + mt * 16 + lg * 4 + r;
          int n = n0 + wn * 64 + nt * 16 + lr;
          float v = (acc[mt][nt][r] + bn[nt]) * sc;
          int b = m >> 11, s = m & 2047, h = n >> 6, hd = n & 63;
          out[(((size_t)(b * H_ + h) * S_ + s) << 6) + hd] = (bf16_t)v;
        }
  } else {  // V: transpose in LDS, write VT[(b*16+h)][hd][s]
    __syncthreads();  // drains vmcnt (incl. dead re-stage) + all waves done
#pragma unroll
    for (int mt = 0; mt < 4; mt++)
#pragma unroll
      for (int nt = 0; nt < 4; nt++)
#pragma unroll
        for (int r = 0; r < 4; r++) {
          int ml = wm * 64 + mt * 16 + lg * 4 + r;
          int nl = wn * 64 + nt * 16 + lr;
          smem[nl * 136 + ml] = (bf16_t)(acc[mt][nt][r] + bn[nt]);
        }
    __syncthreads();
    const int b = m0 >> 11, sbase = m0 & 2047;
#pragma unroll
    for (int c = 0; c < 8; c++) {
      int ci = c * 256 + tid;
      int dl = ci >> 4, sc2 = ci & 15;
      int n = n0 + dl, h = n >> 6, hd = n & 63;
      bf16x8 v = *reinterpret_cast<const bf16x8*>(smem + dl * 136 + sc2 * 8);
      *reinterpret_cast<bf16x8*>(out + ((size_t)((b * H_ + h) << 6) + hd) * S_ + sbase + sc2 * 8) = v;
    }
  }
}

// ---- output GEMM: C[8192x1024] = attn(bf16) @ WoT + bo, f32 out ------------
__global__ __launch_bounds__(256) void out_gemm(const bf16_t* __restrict__ A,
                                                const bf16_t* __restrict__ WT,
                                                const float* __restrict__ bias,
                                                float* __restrict__ out) {
  __shared__ bf16_t smem[32768];
  const int tid = threadIdx.x;
  const int w = tid >> 6, l = tid & 63;
  const int lr = l & 15, lg = l >> 4;
  const int wm = w >> 1, wn = w & 1;
  const int ib = (int)blockIdx.y * 8 + (int)blockIdx.x;
  const int swz = (ib & 7) * 64 + (ib >> 3);
  const int m0 = (swz >> 3) * 128, n0 = (swz & 7) * 128;

  const int row0 = tid >> 3;
  const int ks = (tid & 7) ^ (row0 & 7);
  const bf16_t* aS = A + (size_t)(m0 + row0) * 1024 + ks * 8;
  const bf16_t* bS = WT + (size_t)(n0 + row0) * 1024 + ks * 8;
  const int wsl = w * 512;

  f32x4 acc[4][4];
#pragma unroll
  for (int mt = 0; mt < 4; mt++)
#pragma unroll
    for (int nt = 0; nt < 4; nt++) {
      f32x4 zz = {0.f, 0.f, 0.f, 0.f};
      acc[mt][nt] = zz;
    }

#define STAGE(bi, kt)                                                   \
  do {                                                                  \
    bf16_t* ad = smem + (bi) * 16384 + wsl;                             \
    bf16_t* bd = smem + (bi) * 16384 + 8192 + wsl;                      \
    _Pragma("unroll") for (int c = 0; c < 4; c++) {                     \
      gload_lds16(bS + (size_t)c * 32768 + (kt), bd + c * 2048);        \
      gload_lds16(aS + (size_t)c * 32768 + (kt), ad + c * 2048);        \
    }                                                                   \
  } while (0)

  STAGE(0, 0);
  STAGE(1, 64);
  asm volatile("s_waitcnt vmcnt(8)" ::: "memory");
  __builtin_amdgcn_s_barrier();
  __builtin_amdgcn_sched_barrier(0);

  int buf = 0;
  for (int jt = 0; jt < 16; ++jt) {
    const bf16_t* alds = smem + buf * 16384;
    const bf16_t* blds = alds + 8192;
#pragma unroll
    for (int kk = 0; kk < 2; kk++) {
      bf16x8 af[4], bfr[4];
#pragma unroll
      for (int mt = 0; mt < 4; mt++) {
        int row = wm * 64 + mt * 16 + lr;
        int kc = kk * 4 + lg;
        af[mt] = *reinterpret_cast<const bf16x8*>(alds + row * 64 + ((kc ^ (row & 7)) * 8));
      }
#pragma unroll
      for (int nt = 0; nt < 4; nt++) {
        int row = wn * 64 + nt * 16 + lr;
        int kc = kk * 4 + lg;
        bfr[nt] = *reinterpret_cast<const bf16x8*>(blds + row * 64 + ((kc ^ (row & 7)) * 8));
      }
#pragma unroll
      for (int mt = 0; mt < 4; mt++)
#pragma unroll
        for (int nt = 0; nt < 4; nt++)
          acc[mt][nt] = MFMA(af[mt], bfr[nt], acc[mt][nt]);
    }
    if (jt == 15) break;
    __builtin_amdgcn_sched_barrier(0);
    __builtin_amdgcn_s_barrier();
    __builtin_amdgcn_sched_barrier(0);
    const int tn = (jt + 2 < 16) ? jt + 2 : 15;
    STAGE(buf, tn * 64);
    asm volatile("s_waitcnt vmcnt(8)" ::: "memory");
    __builtin_amdgcn_s_barrier();
    __builtin_amdgcn_sched_barrier(0);
    buf ^= 1;
  }
#undef STAGE

  float bn[4];
#pragma unroll
  for (int nt = 0; nt < 4; nt++) bn[nt] = bias[n0 + wn * 64 + nt * 16 + lr];
#pragma unroll
  for (int mt = 0; mt < 4; mt++)
#pragma unroll
    for (int nt = 0; nt < 4; nt++)
#pragma unroll
      for (int r = 0; r < 4; r++) {
        int m = m0 + wm * 64 + mt * 16 + lg * 4 + r;
        int n = n0 + wn * 64 + nt * 16 + lr;
        out[(size_t)m * D_ + n] = acc[mt][nt][r] + bn[nt];
      }
}

// ---- causal flash attention ------------------------------------------------
// 256 threads = 4 waves; QBLK=128 (wave w owns 32 q-rows: 2 groups of 16).
// K/V LDS fragments read ONCE per wave and shared by both groups (halves LDS
// traffic per unit work). Block handles q-tile pair {p, 15-p}: 34 kv-iters.
// 2-buffer ring, counted vmcnt(4), raw s_barrier.
__global__ __launch_bounds__(256) void attn_k(const bf16_t* __restrict__ qh,
                                              const bf16_t* __restrict__ kh,
                                              const bf16_t* __restrict__ vt,
                                              bf16_t* __restrict__ attn) {
  __shared__ bf16_t kbuf[2][4096];
  __shared__ bf16_t vbuf[2][4096];

  const int tid = threadIdx.x, w = tid >> 6, l = tid & 63;
  const int lr = l & 15, lg = l >> 4;

  // XCD mapping: ib&7 = XCD; each XCD serves 8 bh
  const int ib = (int)blockIdx.y * 8 + (int)blockIdx.x;  // [0,512)
  const int xcd = ib & 7, slot = ib >> 3;
  const int bh = xcd * 8 + (slot & 7);
  const int pr = slot >> 3;  // pair index 0..7
  const int b = bh >> 4, h = bh & 15;

  // staging geometry: chunk i in {0,1}; slot-row zr_i = i*32 + tid>>3
  const int zr0 = tid >> 3, kc = tid & 7;
  const int sks = kc ^ (zr0 & 7);
  const int kprow0 = ((zr0 >> 5) & 1) * 32 + ((zr0 >> 2) & 3) * 8 + ((zr0 >> 4) & 1) * 4 + (zr0 & 3);
  const int zr1 = 32 + zr0;
  const int kprow1 = ((zr1 >> 5) & 1) * 32 + ((zr1 >> 2) & 3) * 8 + ((zr1 >> 4) & 1) * 4 + (zr1 & 3);
  const bf16_t* kbase0 = kh + ((size_t)bh * S_ + kprow0) * HD_ + sks * 8;
  const bf16_t* kbase1 = kh + ((size_t)bh * S_ + kprow1) * HD_ + sks * 8;
  const bf16_t* vbase0 = vt + ((size_t)bh * HD_ + zr0) * S_ + sks * 8;
  const bf16_t* vbase1 = vt + ((size_t)bh * HD_ + zr1) * S_ + sks * 8;

  const int xs7 = lr & 7;
  const int koffA = lr * 64 + ((lg ^ xs7) << 3);
  const int koffB = lr * 64 + (((lg ^ xs7) ^ 4) << 3);
  const int rowlim0 = w * 32 + lr;       // group 0 row (within 128-tile)
  const int rowlim1 = w * 32 + 16 + lr;  // group 1
  const int wact = w * 32 + 31;          // wave-active bound (tile-relative)
  const int wsl = w * 512;

  bf16x8 ones;
#pragma unroll
  for (int i = 0; i < 8; i++) ones[i] = (bf16_t)1.0f;

  for (int half = 0; half < 2; half++) {
    const int qt = half ? (15 - pr) : pr;  // 128-row q-tile index
    const int q0 = qt * 128 + w * 32;
    const int jend = 2 * qt + 1;  // last 64-row kv tile

    const bf16_t* qp0 = qh + ((size_t)bh * S_ + q0 + lr) * HD_ + lg * 8;
    const bf16_t* qp1 = qp0 + 16 * HD_;
    bf16x8 qf00 = *(const bf16x8*)qp0;
    bf16x8 qf01 = *(const bf16x8*)(qp0 + 32);
    bf16x8 qf10 = *(const bf16x8*)qp1;
    bf16x8 qf11 = *(const bf16x8*)(qp1 + 32);

    float mi0 = -1e30f, mi1 = -1e30f;
    f32x4 o0[4], o1[4], os0, os1;
#pragma unroll
    for (int nt = 0; nt < 4; nt++) {
      f32x4 z = {0.f, 0.f, 0.f, 0.f};
      o0[nt] = z; o1[nt] = z;
    }
    {
      f32x4 z = {0.f, 0.f, 0.f, 0.f};
      os0 = z; os1 = z;
    }

    const bf16_t *ks0 = kbase0, *ks1 = kbase1, *vs0 = vbase0, *vs1 = vbase1;
    int jsrc = 0;

#define ISSUE_STAGE(kd, vd)                                     \
    do {                                                        \
      gload_lds16(ks0, (kd));                                   \
      gload_lds16(ks1, (kd) + 2048);                            \
      gload_lds16(vs0, (vd));                                   \
      gload_lds16(vs1, (vd) + 2048);                            \
      if (jsrc < jend) {                                        \
        ks0 += 64 * HD_; ks1 += 64 * HD_; vs0 += 64; vs1 += 64; \
        jsrc++;                                                 \
      }                                                         \
    } while (0)

    // order prev half's dead re-stage before overwriting buf0
    asm volatile("s_waitcnt vmcnt(0)" ::: "memory");

    const bf16_t *rK = kbuf[0], *rV = vbuf[0];
    const bf16_t *rKn = kbuf[1], *rVn = vbuf[1];
    bf16_t *wK = &kbuf[1][wsl], *wV = &vbuf[1][wsl];
    bf16_t *wKn = &kbuf[0][wsl], *wVn = &vbuf[0][wsl];

    ISSUE_STAGE(wKn, wVn);  // tile 0 -> buf0

    for (int jt = 0; jt <= jend; jt++) {
      ISSUE_STAGE(wK, wV);  // tile jt+1 (clamped) -> other buffer
      asm volatile("s_waitcnt vmcnt(4)" ::: "memory");  // stage(jt) landed
      __builtin_amdgcn_s_barrier();
      __builtin_amdgcn_sched_barrier(0);

      const int doff = jt * 64 - qt * 128;  // kv offset relative to q-tile base
      if (doff <= wact) {  // wave-uniform: skip fully-masked tile (FIX: was jt*64)
        f32x4 s0[4], s1[4];
        __builtin_amdgcn_s_setprio(1);
#pragma unroll
        for (int nt = 0; nt < 4; nt++) {
          bf16x8 kf0 = *(const bf16x8*)(rK + koffA + nt * 1024);
          bf16x8 kf1 = *(const bf16x8*)(rK + koffB + nt * 1024);
          f32x4 a = {0.f, 0.f, 0.f, 0.f};
          a = MFMA(kf0, qf00, a);
          a = MFMA(kf1, qf01, a);
          s0[nt] = a;
          f32x4 a2 = {0.f, 0.f, 0.f, 0.f};
          a2 = MFMA(kf0, qf10, a2);
          a2 = MFMA(kf1, qf11, a2);
          s1[nt] = a2;
        }
        __builtin_amdgcn_s_setprio(0);
        if (doff >= 0) {  // diagonal region: kv = doff + pi(nt,lg,r)
#pragma unroll
          for (int nt = 0; nt < 4; nt++) {
            int kvb = doff + ((nt >> 1) << 5) + ((nt & 1) << 2) + lg * 8;
#pragma unroll
            for (int r = 0; r < 4; r++) {
              if (kvb + r > rowlim0) s0[nt][r] = -1e30f;
              if (kvb + r > rowlim1) s1[nt][r] = -1e30f;
            }
          }
        }
        // row max per group: v_max3 tree + cross-copy reduce
        float ma0 = max3f(s0[0][0], s0[0][1], s0[0][2]);
        float ma1 = max3f(s0[0][3], s0[1][0], s0[1][1]);
        float ma2 = max3f(s0[1][2], s0[1][3], s0[2][0]);
        float ma3 = max3f(s0[2][1], s0[2][2], s0[2][3]);
        float ma4 = max3f(s0[3][0], s0[3][1], s0[3][2]);
        float mx0 = fmaxf(max3f(ma0, ma1, ma2), max3f(ma3, ma4, s0[3][3]));
        float mb0 = max3f(s1[0][0], s1[0][1], s1[0][2]);
        float mb1 = max3f(s1[0][3], s1[1][0], s1[1][1]);
        float mb2 = max3f(s1[1][2], s1[1][3], s1[2][0]);
        float mb3 = max3f(s1[2][1], s1[2][2], s1[2][3]);
        float mb4 = max3f(s1[3][0], s1[3][1], s1[3][2]);
        float mx1 = fmaxf(max3f(mb0, mb1, mb2), max3f(mb3, mb4, s1[3][3]));
        mx0 = fmaxf(mx0, __shfl_xor(mx0, 16));
        mx0 = fmaxf(mx0, __shfl_xor(mx0, 32));
        mx1 = fmaxf(mx1, __shfl_xor(mx1, 16));
        mx1 = fmaxf(mx1, __shfl_xor(mx1, 32));
        // T13 defer-max (combined)
        if (!__all((mx0 <= mi0 + 8.0f) && (mx1 <= mi1 + 8.0f))) {
          float mn0 = fmaxf(mi0, mx0), mn1 = fmaxf(mi1, mx1);
          float al0 = __builtin_amdgcn_exp2f((mi0 - mn0) * LOG2E);
          float al1 = __builtin_amdgcn_exp2f((mi1 - mn1) * LOG2E);
          mi0 = mn0; mi1 = mn1;
#pragma unroll
          for (int r = 0; r < 4; r++) {
            float a0r = __shfl(al0, lg * 4 + r);
            o0[0][r] *= a0r; o0[1][r] *= a0r; o0[2][r] *= a0r; o0[3][r] *= a0r;
            os0[r] *= a0r;
            float a1r = __shfl(al1, lg * 4 + r);
            o1[0][r] *= a1r; o1[1][r] *= a1r; o1[2][r] *= a1r; o1[3][r] *= a1r;
            os1[r] *= a1r;
          }
        }
        const float msc0 = mi0 * LOG2E, msc1 = mi1 * LOG2E;
#pragma unroll
        for (int nt = 0; nt < 4; nt++)
#pragma unroll
          for (int r = 0; r < 4; r++) {
            s0[nt][r] = __builtin_amdgcn_exp2f(s0[nt][r] * LOG2E - msc0);
            s1[nt][r] = __builtin_amdgcn_exp2f(s1[nt][r] * LOG2E - msc1);
          }
        // P -> PA fragments: pure in-lane packs (per group)
        uint32_t pk0[8], pk1[8];
#pragma unroll
        for (int nt = 0; nt < 4; nt++) {
          bf16x2_t p0lo = {(bf16_t)s0[nt][0], (bf16_t)s0[nt][1]};
          bf16x2_t p0hi = {(bf16_t)s0[nt][2], (bf16_t)s0[nt][3]};
          pk0[nt * 2] = __builtin_bit_cast(uint32_t, p0lo);
          pk0[nt * 2 + 1] = __builtin_bit_cast(uint32_t, p0hi);
          bf16x2_t p1lo = {(bf16_t)s1[nt][0], (bf16_t)s1[nt][1]};
          bf16x2_t p1hi = {(bf16_t)s1[nt][2], (bf16_t)s1[nt][3]};
          pk1[nt * 2] = __builtin_bit_cast(uint32_t, p1lo);
          pk1[nt * 2 + 1] = __builtin_bit_cast(uint32_t, p1hi);
        }
        i32x4 w00 = {(int)pk0[0], (int)pk0[1], (int)pk0[2], (int)pk0[3]};
        i32x4 w01 = {(int)pk0[4], (int)pk0[5], (int)pk0[6], (int)pk0[7]};
        i32x4 w10 = {(int)pk1[0], (int)pk1[1], (int)pk1[2], (int)pk1[3]};
        i32x4 w11 = {(int)pk1[4], (int)pk1[5], (int)pk1[6], (int)pk1[7]};
        bf16x8 pa00 = __builtin_bit_cast(bf16x8, w00);
        bf16x8 pa01 = __builtin_bit_cast(bf16x8, w01);
        bf16x8 pa10 = __builtin_bit_cast(bf16x8, w10);
        bf16x8 pa11 = __builtin_bit_cast(bf16x8, w11);
        __builtin_amdgcn_s_setprio(1);
#pragma unroll
        for (int ntd = 0; ntd < 4; ntd++) {
          bf16x8 vf0 = *(const bf16x8*)(rV + koffA + ntd * 1024);
          bf16x8 vf1 = *(const bf16x8*)(rV + koffB + ntd * 1024);
          o0[ntd] = MFMA(pa00, vf0, o0[ntd]);
          o0[ntd] = MFMA(pa01, vf1, o0[ntd]);
          o1[ntd] = MFMA(pa10, vf0, o1[ntd]);
          o1[ntd] = MFMA(pa11, vf1, o1[ntd]);
        }
        os0 = MFMA(pa00, ones, os0);
        os0 = MFMA(pa01, ones, os0);
        os1 = MFMA(pa10, ones, os1);
        os1 = MFMA(pa11, ones, os1);
        __builtin_amdgcn_s_setprio(0);
      }

      __builtin_amdgcn_sched_barrier(0);
      __builtin_amdgcn_s_barrier();  // WAR: reads done before buf reuse
      __builtin_amdgcn_sched_barrier(0);
      { const bf16_t* t = rK; rK = rKn; rKn = t; t = rV; rV = rVn; rVn = t; }
      { bf16_t* t = wK; wK = wKn; wKn = t; t = wV; wV = wVn; wVn = t; }
    }
#undef ISSUE_STAGE
    // epilogue: attn[b][s][h*64+hd], group g rows = q0 + g*16 + lg*4 + r
#pragma unroll
    for (int r = 0; r < 4; r++) {
      float rinv0 = 1.f / os0[r];
      float rinv1 = 1.f / os1[r];
      int srw0 = q0 + lg * 4 + r;
      int srw1 = srw0 + 16;
#pragma unroll
      for (int ntd = 0; ntd < 4; ntd++) {
        attn[((size_t)(b * S_ + srw0)) * D_ + h * 64 + ntd * 16 + lr] =
            (bf16_t)(o0[ntd][r] * rinv0);
        attn[((size_t)(b * S_ + srw1)) * D_ + h * 64 + ntd * 16 + lr] =
            (bf16_t)(o1[ntd][r] * rinv1);
      }
    }
  }
}

extern "C" void kernel_launch(void* const* d_in, const int* in_sizes, int n_in,
                              void* d_out, int out_size, void* d_ws, size_t ws_size,
                              hipStream_t stream) {
  (void)in_sizes; (void)n_in; (void)out_size; (void)ws_size;
  const float* q  = (const float*)d_in[0];
  const float* k  = (const float*)d_in[1];
  const float* v  = (const float*)d_in[2];
  // d_in[3] = mask: causal triu, hard-coded in attn_k
  const float* Wq = (const float*)d_in[4];
  const float* bq = (const float*)d_in[5];
  const float* Wk = (const float*)d_in[6];
  const float* bk = (const float*)d_in[7];
  const float* Wv = (const float*)d_in[8];
  const float* bv = (const float*)d_in[9];
  const float* Wo = (const float*)d_in[10];
  const float* bo = (const float*)d_in[11];

  char* ws = (char*)d_ws;
  bf16_t* wt0 = (bf16_t*)(ws + (0ull << 20));   // 4 x 2MB transposed weights
  bf16_t* wto = (bf16_t*)(ws + (6ull << 20));
  bf16_t* atb = (bf16_t*)(ws + (8ull << 20));   // attn output, 16MB
  bf16_t* qhb = (bf16_t*)(ws + (56ull << 20));  // Qh/Kh/VT, 3 x 16MB
  bf16_t* khb = (bf16_t*)(ws + (72ull << 20));
  bf16_t* vtb = (bf16_t*)(ws + (88ull << 20));

  dim3 tb(256);
  wt_kernel<<<dim3(32, 32, 4), tb, 0, stream>>>(Wq, Wk, Wv, Wo, wt0);
  qkv_mm<<<dim3(8, 64, 3), tb, 0, stream>>>(q, k, v, wt0, bq, bk, bv, qhb);
  attn_k<<<dim3(8, 64), tb, 0, stream>>>(qhb, khb, vtb, atb);
  out_gemm<<<dim3(8, 64), tb, 0, stream>>>(atb, wto, bo, (float*)d_out);
}